// Round 1
// baseline (13691.635 us; speedup 1.0000x reference)
//
#include <hip/hip_runtime.h>
#include <stdint.h>

typedef __attribute__((ext_vector_type(4))) float    f32x4;
typedef __attribute__((ext_vector_type(8))) short    s16x8;
typedef __attribute__((ext_vector_type(4))) uint16_t u16x4;
typedef __attribute__((ext_vector_type(8))) uint16_t u16x8;

__device__ __forceinline__ uint16_t f2bf(float f) {
    uint32_t u = __float_as_uint(f);
    u = u + 0x7FFFu + ((u >> 16) & 1u);
    return (uint16_t)(u >> 16);
}
__device__ __forceinline__ float bf2f(uint16_t h) {
    return __uint_as_float(((uint32_t)h) << 16);
}
__device__ __forceinline__ float sigm(float x) {
    return __builtin_amdgcn_rcpf(1.0f + __expf(-x));
}
__device__ __forceinline__ float tanh_f(float x) {
    float e = __expf(2.0f * x);
    return 1.0f - 2.0f * __builtin_amdgcn_rcpf(e + 1.0f);
}

// ---------------------------------------------------------------------------
// Prep: cast Wih/Whh to bf16, build concat qkv bias
// ---------------------------------------------------------------------------
__global__ void kprep(const float* __restrict__ wihf, const float* __restrict__ wihb,
                      const float* __restrict__ whhf, const float* __restrict__ whhb,
                      const float* __restrict__ bq, const float* __restrict__ bk,
                      const float* __restrict__ bv,
                      uint16_t* __restrict__ wihbf, uint16_t* __restrict__ whhbf,
                      float* __restrict__ biasqkv) {
    size_t i = (size_t)blockIdx.x * 256 + threadIdx.x;
    if (i < 2097152) {
        wihbf[i] = f2bf(wihf[i]);
    } else if (i < 4194304) {
        wihbf[i] = f2bf(wihb[i - 2097152]);
    } else if (i < 5242880) {
        whhbf[i - 4194304] = f2bf(whhf[i - 4194304]);
    } else if (i < 6291456) {
        whhbf[i - 4194304] = f2bf(whhb[i - 5242880]);
    } else if (i < 6294528) {
        size_t k = i - 6291456;
        biasqkv[k] = (k < 1024) ? bq[k] : (k < 2048) ? bk[k - 1024] : bv[k - 2048];
    }
}

// transpose+cast Wq/Wk/Wv/Wo (1024x1024 f32 [k][n]) -> [z][n][k] bf16
__global__ void ktrans(const float* __restrict__ Wq, const float* __restrict__ Wk,
                       const float* __restrict__ Wv, const float* __restrict__ Wo,
                       uint16_t* __restrict__ out) {
    const float* W = (blockIdx.z == 0) ? Wq : (blockIdx.z == 1) ? Wk : (blockIdx.z == 2) ? Wv : Wo;
    __shared__ float t[32][33];
    int x  = blockIdx.x * 32 + threadIdx.x;
    int y0 = blockIdx.y * 32 + threadIdx.y;
#pragma unroll
    for (int i = 0; i < 4; i++)
        t[threadIdx.y + 8 * i][threadIdx.x] = W[(size_t)(y0 + 8 * i) * 1024 + x];
    __syncthreads();
    int ox  = blockIdx.y * 32 + threadIdx.x;
    int oy0 = blockIdx.x * 32 + threadIdx.y;
#pragma unroll
    for (int i = 0; i < 4; i++)
        out[((size_t)blockIdx.z * 1024 + oy0 + 8 * i) * 1024 + ox] = f2bf(t[threadIdx.x][threadIdx.y + 8 * i]);
}

// ---------------------------------------------------------------------------
// Generic bf16 MFMA GEMM: C[M][N] = A[M][1024] * B[N][1024]^T + bias, bf16 out.
// A is f32 (AF32=1, cast during staging) or bf16. 128x128 tile, BK=32, 4 waves.
// ---------------------------------------------------------------------------
template <int AF32>
__global__ __launch_bounds__(256) void gemm_k(const void* __restrict__ Av,
                                              const uint16_t* __restrict__ B,
                                              const float* __restrict__ bias,
                                              uint16_t* __restrict__ C, int M, int N) {
    __shared__ uint16_t lA[128 * 40];
    __shared__ uint16_t lB[128 * 40];
    const int tid = threadIdx.x;
    const int m0 = blockIdx.y * 128, n0 = blockIdx.x * 128;
    const int srow = tid >> 1, skh = (tid & 1) * 16;
    const int lane = tid & 63, wid = tid >> 6;
    const int wm = wid >> 1, wn = wid & 1;
    const int fn = lane & 15, fq = lane >> 4;
    f32x4 acc[4][4];
#pragma unroll
    for (int a = 0; a < 4; a++)
#pragma unroll
        for (int b = 0; b < 4; b++) acc[a][b] = f32x4{0.f, 0.f, 0.f, 0.f};

    for (int kt = 0; kt < 32; kt++) {
        if (AF32) {
            const float* A = (const float*)Av + (size_t)(m0 + srow) * 1024 + kt * 32 + skh;
#pragma unroll
            for (int i = 0; i < 4; i++) {
                f32x4 t = *(const f32x4*)(A + i * 4);
                u16x4 p;
                p[0] = f2bf(t[0]); p[1] = f2bf(t[1]); p[2] = f2bf(t[2]); p[3] = f2bf(t[3]);
                *(u16x4*)&lA[srow * 40 + skh + i * 4] = p;
            }
        } else {
            const uint16_t* A = (const uint16_t*)Av + (size_t)(m0 + srow) * 1024 + kt * 32 + skh;
            *(u16x8*)&lA[srow * 40 + skh]     = *(const u16x8*)(A);
            *(u16x8*)&lA[srow * 40 + skh + 8] = *(const u16x8*)(A + 8);
        }
        const uint16_t* Bp = B + (size_t)(n0 + srow) * 1024 + kt * 32 + skh;
        *(u16x8*)&lB[srow * 40 + skh]     = *(const u16x8*)(Bp);
        *(u16x8*)&lB[srow * 40 + skh + 8] = *(const u16x8*)(Bp + 8);
        __syncthreads();
        s16x8 af[4], bfv[4];
#pragma unroll
        for (int mt = 0; mt < 4; mt++) af[mt] = *(const s16x8*)&lA[(wm * 64 + mt * 16 + fn) * 40 + fq * 8];
#pragma unroll
        for (int nt = 0; nt < 4; nt++) bfv[nt] = *(const s16x8*)&lB[(wn * 64 + nt * 16 + fn) * 40 + fq * 8];
#pragma unroll
        for (int mt = 0; mt < 4; mt++)
#pragma unroll
            for (int nt = 0; nt < 4; nt++)
                acc[mt][nt] = __builtin_amdgcn_mfma_f32_16x16x32_bf16(af[mt], bfv[nt], acc[mt][nt], 0, 0, 0);
        __syncthreads();
    }
#pragma unroll
    for (int nt = 0; nt < 4; nt++) {
        int col = n0 + wn * 64 + nt * 16 + fn;
        float bvv = bias ? bias[col] : 0.0f;
#pragma unroll
        for (int mt = 0; mt < 4; mt++) {
            int row0 = m0 + wm * 64 + mt * 16 + fq * 4;
#pragma unroll
            for (int i = 0; i < 4; i++)
                C[(size_t)(row0 + i) * N + col] = f2bf(acc[mt][nt][i] + bvv);
        }
    }
}

// ---------------------------------------------------------------------------
// LSTM recurrence. 64 WGs x 64 threads (1 wave). WG = (dir, 16-hid slice j).
// Whh slice (64 gates x 512 k, bf16) resident in 256 VGPRs as MFMA B-frags.
// Per step: (16,512)@(512,64) via 64 MFMAs; h exchanged through enc buffer
// with a device-scope monotonic counter barrier per direction.
// enc layout: [dir][p][b][512] bf16 (doubles as the final sequence output).
// xs layout:  [dir][b*1024+p][2048] bf16 (gate order i,f,g,o).
// ---------------------------------------------------------------------------
__global__ __launch_bounds__(64, 1) void krecur(const uint16_t* __restrict__ whhbf,
                                                const uint16_t* __restrict__ xs,
                                                uint16_t* __restrict__ enc,
                                                uint32_t* cnt) {
    const int wg = blockIdx.x;
    const int dir = wg >> 5, j = wg & 31;
    const int lane = threadIdx.x;
    const int n = lane & 15, q = lane >> 4;

    s16x8 Bf[4][16];
    {
        const uint16_t* wb = whhbf + (size_t)dir * 2048 * 512;
#pragma unroll
        for (int t4 = 0; t4 < 4; t4++)
#pragma unroll
            for (int s = 0; s < 16; s++)
                Bf[t4][s] = *(const s16x8*)(wb + (size_t)(t4 * 512 + j * 16 + n) * 512 + s * 32 + q * 8);
    }
    float c[4] = {0.f, 0.f, 0.f, 0.f};
    const uint16_t* xsp = xs + (size_t)dir * 16384 * 2048;
    uint16_t* encp = enc + (size_t)dir * 1024 * 16 * 512;
    uint32_t* mycnt = cnt + dir;

    for (int t = 0; t < 1024; t++) {
        const int p = dir ? (1023 - t) : t;
        f32x4 acc[4];
#pragma unroll
        for (int t4 = 0; t4 < 4; t4++) acc[t4] = f32x4{0.f, 0.f, 0.f, 0.f};

        if (t > 0) {
            if (lane == 0) {
                while (__hip_atomic_load(mycnt, __ATOMIC_RELAXED, __HIP_MEMORY_SCOPE_AGENT) <
                       (uint32_t)(32 * t)) { }
            }
            __threadfence();  // acquire: invalidate L1/L2 so h slices are fresh
            const int pp = dir ? (p + 1) : (p - 1);
            const uint16_t* hrow = encp + ((size_t)pp * 16 + n) * 512 + q * 8;
            s16x8 Af[16];
#pragma unroll
            for (int s = 0; s < 16; s++) Af[s] = *(const s16x8*)(hrow + s * 32);
#pragma unroll
            for (int s = 0; s < 16; s++) {
#pragma unroll
                for (int t4 = 0; t4 < 4; t4++)
                    acc[t4] = __builtin_amdgcn_mfma_f32_16x16x32_bf16(Af[s], Bf[t4][s], acc[t4], 0, 0, 0);
            }
        }
        float g4[4][4];
#pragma unroll
        for (int t4 = 0; t4 < 4; t4++)
#pragma unroll
            for (int i = 0; i < 4; i++) {
                uint16_t xv = xsp[((size_t)(4 * q + i) * 1024 + p) * 2048 + t4 * 512 + j * 16 + n];
                g4[t4][i] = acc[t4][i] + bf2f(xv);
            }
#pragma unroll
        for (int i = 0; i < 4; i++) {
            float ig = sigm(g4[0][i]);
            float fg = sigm(g4[1][i]);
            float gg = tanh_f(g4[2][i]);
            float og = sigm(g4[3][i]);
            c[i] = fg * c[i] + ig * gg;
            float hv = og * tanh_f(c[i]);
            encp[((size_t)p * 16 + 4 * q + i) * 512 + j * 16 + n] = f2bf(hv);
        }
        __threadfence();  // release: push h slice to coherence point
        if (lane == 0)
            __hip_atomic_fetch_add(mycnt, 1u, __ATOMIC_RELAXED, __HIP_MEMORY_SCOPE_AGENT);
    }
}

// ---------------------------------------------------------------------------
// Span mean-pool + LayerNorm1. One block per (b,s). feat f32 + bf16 copies.
// ---------------------------------------------------------------------------
__global__ __launch_bounds__(256) void kpool(const uint16_t* __restrict__ enc,
                                             const int* __restrict__ heads,
                                             const int* __restrict__ tails,
                                             const float* __restrict__ g,
                                             const float* __restrict__ bb,
                                             float* __restrict__ feat,
                                             uint16_t* __restrict__ featb) {
    const int m = blockIdx.x;
    const int b = m >> 5;
    const int tid = threadIdx.x;
    const int h0 = tid * 4;
    const int dir = h0 >> 9, hid = h0 & 511;
    int p0 = heads[m] + 1; if (p0 < 0) p0 = 0;
    int p1 = tails[m];     if (p1 > 1024) p1 = 1024;
    float a0 = 0, a1 = 0, a2 = 0, a3 = 0;
    int cnt = p1 - p0; if (cnt < 1) cnt = 1;
    for (int p = p0; p < p1; p++) {
        const uint16_t* e = enc + (((size_t)dir * 1024 + p) * 16 + b) * 512 + hid;
        u16x4 hv = *(const u16x4*)e;
        a0 += bf2f(hv[0]); a1 += bf2f(hv[1]); a2 += bf2f(hv[2]); a3 += bf2f(hv[3]);
    }
    float inv = 1.0f / (float)cnt;
    float x0 = a0 * inv, x1 = a1 * inv, x2 = a2 * inv, x3 = a3 * inv;
    float ls = x0 + x1 + x2 + x3;
    float lq = x0 * x0 + x1 * x1 + x2 * x2 + x3 * x3;
#pragma unroll
    for (int o = 32; o > 0; o >>= 1) { ls += __shfl_down(ls, o); lq += __shfl_down(lq, o); }
    __shared__ float rs_[4], rq_[4], st_[2];
    const int lane = tid & 63, wid = tid >> 6;
    if (lane == 0) { rs_[wid] = ls; rq_[wid] = lq; }
    __syncthreads();
    if (tid == 0) {
        float S = rs_[0] + rs_[1] + rs_[2] + rs_[3];
        float Q = rq_[0] + rq_[1] + rq_[2] + rq_[3];
        float mean = S * (1.0f / 1024.0f);
        float var = Q * (1.0f / 1024.0f) - mean * mean;
        st_[0] = mean;
        st_[1] = rsqrtf(var + 1e-7f);
    }
    __syncthreads();
    float mean = st_[0], rstd = st_[1];
    size_t ob = (size_t)m * 1024 + h0;
    float y0 = (x0 - mean) * rstd * g[h0 + 0] + bb[h0 + 0];
    float y1 = (x1 - mean) * rstd * g[h0 + 1] + bb[h0 + 1];
    float y2 = (x2 - mean) * rstd * g[h0 + 2] + bb[h0 + 2];
    float y3 = (x3 - mean) * rstd * g[h0 + 3] + bb[h0 + 3];
    feat[ob + 0] = y0; feat[ob + 1] = y1; feat[ob + 2] = y2; feat[ob + 3] = y3;
    featb[ob + 0] = f2bf(y0); featb[ob + 1] = f2bf(y1);
    featb[ob + 2] = f2bf(y2); featb[ob + 3] = f2bf(y3);
}

// ---------------------------------------------------------------------------
// Attention over S=32, per (b, head). One wave per block.
// ---------------------------------------------------------------------------
__global__ __launch_bounds__(64) void kattn(const uint16_t* __restrict__ qkv,
                                            const int* __restrict__ am,
                                            uint16_t* __restrict__ ctxb) {
    const int bb_ = blockIdx.x >> 4, nh = blockIdx.x & 15;
    const int lane = threadIdx.x;
    __shared__ float qs[32][65], ks[32][65], vs[32][65];
    __shared__ float ps[32][33];
    for (int s = 0; s < 32; s++) {
        const uint16_t* base = qkv + (size_t)(bb_ * 32 + s) * 3072 + nh * 64;
        qs[s][lane] = bf2f(base[lane]);
        ks[s][lane] = bf2f(base[1024 + lane]);
        vs[s][lane] = bf2f(base[2048 + lane]);
    }
    __syncthreads();
    const int r = lane >> 1, ch = (lane & 1) * 16;
    const int amr = am[bb_ * 32 + r];
    float sc[16];
#pragma unroll
    for (int c0 = 0; c0 < 16; c0++) {
        int cc = ch + c0;
        float a = 0;
        for (int d = 0; d < 64; d++) a += qs[r][d] * ks[cc][d];
        a *= 0.125f;
        if (!(amr && am[bb_ * 32 + cc])) a = -1e9f;
        sc[c0] = a;
    }
    float mx = sc[0];
#pragma unroll
    for (int c0 = 1; c0 < 16; c0++) mx = fmaxf(mx, sc[c0]);
    mx = fmaxf(mx, __shfl_xor(mx, 1));
    float se = 0;
#pragma unroll
    for (int c0 = 0; c0 < 16; c0++) { sc[c0] = __expf(sc[c0] - mx); se += sc[c0]; }
    se += __shfl_xor(se, 1);
    float inv = __builtin_amdgcn_rcpf(se);
#pragma unroll
    for (int c0 = 0; c0 < 16; c0++) ps[r][ch + c0] = sc[c0] * inv;
    __syncthreads();
    for (int r2 = 0; r2 < 32; r2++) {
        float a = 0;
        for (int cc = 0; cc < 32; cc++) a += ps[r2][cc] * vs[cc][lane];
        ctxb[(size_t)(bb_ * 32 + r2) * 1024 + nh * 64 + lane] = f2bf(a);
    }
}

// ---------------------------------------------------------------------------
// LN2 over (oproj + feat residual)
// ---------------------------------------------------------------------------
__global__ __launch_bounds__(256) void kln2(const uint16_t* __restrict__ oproj,
                                            const float* __restrict__ feat,
                                            const float* __restrict__ g,
                                            const float* __restrict__ bb,
                                            float* __restrict__ feat2) {
    const int m = blockIdx.x, tid = threadIdx.x;
    const int h0 = tid * 4;
    size_t base = (size_t)m * 1024 + h0;
    u16x4 ov = *(const u16x4*)(oproj + base);
    float x0 = bf2f(ov[0]) + feat[base + 0];
    float x1 = bf2f(ov[1]) + feat[base + 1];
    float x2 = bf2f(ov[2]) + feat[base + 2];
    float x3 = bf2f(ov[3]) + feat[base + 3];
    float ls = x0 + x1 + x2 + x3;
    float lq = x0 * x0 + x1 * x1 + x2 * x2 + x3 * x3;
#pragma unroll
    for (int o = 32; o > 0; o >>= 1) { ls += __shfl_down(ls, o); lq += __shfl_down(lq, o); }
    __shared__ float rs_[4], rq_[4], st_[2];
    const int lane = tid & 63, wid = tid >> 6;
    if (lane == 0) { rs_[wid] = ls; rq_[wid] = lq; }
    __syncthreads();
    if (tid == 0) {
        float S = rs_[0] + rs_[1] + rs_[2] + rs_[3];
        float Q = rq_[0] + rq_[1] + rq_[2] + rq_[3];
        float mean = S * (1.0f / 1024.0f);
        float var = Q * (1.0f / 1024.0f) - mean * mean;
        st_[0] = mean;
        st_[1] = rsqrtf(var + 1e-7f);
    }
    __syncthreads();
    float mean = st_[0], rstd = st_[1];
    feat2[base + 0] = (x0 - mean) * rstd * g[h0 + 0] + bb[h0 + 0];
    feat2[base + 1] = (x1 - mean) * rstd * g[h0 + 1] + bb[h0 + 1];
    feat2[base + 2] = (x2 - mean) * rstd * g[h0 + 2] + bb[h0 + 2];
    feat2[base + 3] = (x3 - mean) * rstd * g[h0 + 3] + bb[h0 + 3];
}

// ---------------------------------------------------------------------------
// Classifier + CE + focal. One wave per (b,s); atomic partials.
// ---------------------------------------------------------------------------
__global__ __launch_bounds__(64) void kloss(const float* __restrict__ feat2,
                                            const float* __restrict__ Wc,
                                            const float* __restrict__ bc,
                                            const int* __restrict__ labels,
                                            const int* __restrict__ am,
                                            const float* __restrict__ wf,
                                            float* __restrict__ accum) {
    const int m = blockIdx.x, lane = threadIdx.x;
    float l0 = 0, l1 = 0, l2 = 0;
    for (int k = lane; k < 1024; k += 64) {
        float f = feat2[(size_t)m * 1024 + k];
        l0 += f * Wc[k * 3 + 0];
        l1 += f * Wc[k * 3 + 1];
        l2 += f * Wc[k * 3 + 2];
    }
#pragma unroll
    for (int o = 32; o > 0; o >>= 1) {
        l0 += __shfl_down(l0, o);
        l1 += __shfl_down(l1, o);
        l2 += __shfl_down(l2, o);
    }
    if (lane == 0) {
        l0 += bc[0]; l1 += bc[1]; l2 += bc[2];
        float mx = fmaxf(l0, fmaxf(l1, l2));
        float e0 = __expf(l0 - mx), e1 = __expf(l1 - mx), e2 = __expf(l2 - mx);
        float lse = mx + __logf(e0 + e1 + e2);
        float lp[3] = {l0 - lse, l1 - lse, l2 - lse};
        int lab = labels[m];
        float validf = (lab >= 0) ? 1.0f : 0.0f;
        int labc = lab < 0 ? 0 : lab;
        float amv = (am[m] != 0) ? 1.0f : 0.0f;
        float spanm = amv * validf;
        float ce = -lp[labc] * wf[m];
        float pt = __expf(lp[labc]);
        float om = 1.0f - pt;
        float ft = -(om * om * lp[labc]);
        atomicAdd(accum + 0, ce * spanm);
        atomicAdd(accum + 1, spanm);
        atomicAdd(accum + 2, ft * validf);
        atomicAdd(accum + 3, validf);
    }
}

__global__ void kfinal(const float* __restrict__ accum, float* __restrict__ out) {
    out[0] = accum[0] / fmaxf(accum[1], 1.0f) + accum[2] / fmaxf(accum[3], 1.0f);
}

// ---------------------------------------------------------------------------
extern "C" void kernel_launch(void* const* d_in, const int* in_sizes, int n_in,
                              void* d_out, int out_size, void* d_ws, size_t ws_size,
                              hipStream_t stream) {
    const float* hs   = (const float*)d_in[0];
    const int* heads  = (const int*)d_in[1];
    const int* tails  = (const int*)d_in[2];
    const int* amask  = (const int*)d_in[3];
    const int* labels = (const int*)d_in[4];
    const float* wfac = (const float*)d_in[5];
    const float* wihf = (const float*)d_in[6];
    const float* whhf = (const float*)d_in[7];
    const float* lbf  = (const float*)d_in[8];
    const float* wihb = (const float*)d_in[9];
    const float* whhb = (const float*)d_in[10];
    const float* lbb  = (const float*)d_in[11];
    const float* ln1g = (const float*)d_in[12];
    const float* ln1b = (const float*)d_in[13];
    const float* Wq   = (const float*)d_in[14];
    const float* bq   = (const float*)d_in[15];
    const float* Wk   = (const float*)d_in[16];
    const float* bk   = (const float*)d_in[17];
    const float* Wv   = (const float*)d_in[18];
    const float* bv   = (const float*)d_in[19];
    const float* Wo   = (const float*)d_in[20];
    const float* bo   = (const float*)d_in[21];
    const float* ln2g = (const float*)d_in[22];
    const float* ln2b = (const float*)d_in[23];
    const float* Wc   = (const float*)d_in[24];
    const float* bc   = (const float*)d_in[25];

    char* ws = (char*)d_ws;
    uint32_t* cnt   = (uint32_t*)(ws + 0);
    float* accum    = (float*)(ws + 64);
    uint16_t* whhbf = (uint16_t*)(ws + 256);
    uint16_t* wihbf = (uint16_t*)(ws + 4194560);      // 256 + 4 MiB
    uint16_t* wqkvo = (uint16_t*)(ws + 12583168);     // + 8 MiB
    float* biasqkv  = (float*)(ws + 20971776);        // + 8 MiB
    uint16_t* xs    = (uint16_t*)(ws + 20984064);     // + 12 KiB
    uint16_t* enc   = (uint16_t*)(ws + 155201792);    // + 128 MiB
    float* feat     = (float*)(ws + 188756224);       // + 32 MiB
    uint16_t* featb = (uint16_t*)(ws + 190853376);
    uint16_t* qkvb  = (uint16_t*)(ws + 191901952);
    uint16_t* ctxb  = (uint16_t*)(ws + 195047680);
    uint16_t* oprojb= (uint16_t*)(ws + 196096256);
    float* feat2    = (float*)(ws + 197144832);       // end ~199.3 MB

    hipMemsetAsync(ws, 0, 256, stream);  // counters + loss accumulators

    kprep<<<24588, 256, 0, stream>>>(wihf, wihb, whhf, whhb, bq, bk, bv, wihbf, whhbf, biasqkv);
    ktrans<<<dim3(32, 32, 4), dim3(32, 8), 0, stream>>>(Wq, Wk, Wv, Wo, wqkvo);

    // xs GEMMs: (16384x1024) @ (1024x2048)^T per direction
    gemm_k<1><<<dim3(16, 128), 256, 0, stream>>>(hs, wihbf, lbf, xs, 16384, 2048);
    gemm_k<1><<<dim3(16, 128), 256, 0, stream>>>(hs, wihbf + (size_t)2048 * 1024, lbb,
                                                 xs + (size_t)16384 * 2048, 16384, 2048);

    krecur<<<64, 64, 0, stream>>>(whhbf, xs, enc, cnt);

    kpool<<<512, 256, 0, stream>>>(enc, heads, tails, ln1g, ln1b, feat, featb);

    gemm_k<0><<<dim3(24, 4), 256, 0, stream>>>(featb, wqkvo, biasqkv, qkvb, 512, 3072);

    kattn<<<256, 64, 0, stream>>>(qkvb, amask, ctxb);

    gemm_k<0><<<dim3(8, 4), 256, 0, stream>>>(ctxb, wqkvo + (size_t)3072 * 1024, bo, oprojb, 512, 1024);

    kln2<<<512, 256, 0, stream>>>(oprojb, feat, ln2g, ln2b, feat2);
    kloss<<<512, 64, 0, stream>>>(feat2, Wc, bc, labels, amask, wfac, accum);
    kfinal<<<1, 1, 0, stream>>>(accum, (float*)d_out);
}

// Round 3
// 6597.998 us; speedup vs baseline: 2.0751x; 2.0751x over previous
//
#include <hip/hip_runtime.h>
#include <stdint.h>

typedef __attribute__((ext_vector_type(4))) float    f32x4;
typedef __attribute__((ext_vector_type(8))) short    s16x8;
typedef __attribute__((ext_vector_type(4))) uint16_t u16x4;
typedef __attribute__((ext_vector_type(8))) uint16_t u16x8;

__device__ __forceinline__ uint16_t f2bf(float f) {
    uint32_t u = __float_as_uint(f);
    u = u + 0x7FFFu + ((u >> 16) & 1u);
    return (uint16_t)(u >> 16);
}
__device__ __forceinline__ float bf2f(uint16_t h) {
    return __uint_as_float(((uint32_t)h) << 16);
}
__device__ __forceinline__ float sigm(float x) {
    return __builtin_amdgcn_rcpf(1.0f + __expf(-x));
}
__device__ __forceinline__ float tanh_f(float x) {
    float e = __expf(2.0f * x);
    return 1.0f - 2.0f * __builtin_amdgcn_rcpf(e + 1.0f);
}

// ---------------------------------------------------------------------------
// Prep: cast Wih/Whh to bf16, build concat qkv bias
// ---------------------------------------------------------------------------
__global__ void kprep(const float* __restrict__ wihf, const float* __restrict__ wihb,
                      const float* __restrict__ whhf, const float* __restrict__ whhb,
                      const float* __restrict__ bq, const float* __restrict__ bk,
                      const float* __restrict__ bv,
                      uint16_t* __restrict__ wihbf, uint16_t* __restrict__ whhbf,
                      float* __restrict__ biasqkv) {
    size_t i = (size_t)blockIdx.x * 256 + threadIdx.x;
    if (i < 2097152) {
        wihbf[i] = f2bf(wihf[i]);
    } else if (i < 4194304) {
        wihbf[i] = f2bf(wihb[i - 2097152]);
    } else if (i < 5242880) {
        whhbf[i - 4194304] = f2bf(whhf[i - 4194304]);
    } else if (i < 6291456) {
        whhbf[i - 4194304] = f2bf(whhb[i - 5242880]);
    } else if (i < 6294528) {
        size_t k = i - 6291456;
        biasqkv[k] = (k < 1024) ? bq[k] : (k < 2048) ? bk[k - 1024] : bv[k - 2048];
    }
}

// transpose+cast Wq/Wk/Wv/Wo (1024x1024 f32 [k][n]) -> [z][n][k] bf16
__global__ void ktrans(const float* __restrict__ Wq, const float* __restrict__ Wk,
                       const float* __restrict__ Wv, const float* __restrict__ Wo,
                       uint16_t* __restrict__ out) {
    const float* W = (blockIdx.z == 0) ? Wq : (blockIdx.z == 1) ? Wk : (blockIdx.z == 2) ? Wv : Wo;
    __shared__ float t[32][33];
    int x  = blockIdx.x * 32 + threadIdx.x;
    int y0 = blockIdx.y * 32 + threadIdx.y;
#pragma unroll
    for (int i = 0; i < 4; i++)
        t[threadIdx.y + 8 * i][threadIdx.x] = W[(size_t)(y0 + 8 * i) * 1024 + x];
    __syncthreads();
    int ox  = blockIdx.y * 32 + threadIdx.x;
    int oy0 = blockIdx.x * 32 + threadIdx.y;
#pragma unroll
    for (int i = 0; i < 4; i++)
        out[((size_t)blockIdx.z * 1024 + oy0 + 8 * i) * 1024 + ox] = f2bf(t[threadIdx.x][threadIdx.y + 8 * i]);
}

// ---------------------------------------------------------------------------
// Generic bf16 MFMA GEMM: C[M][N] = A[M][1024] * B[N][1024]^T + bias, bf16 out.
// ---------------------------------------------------------------------------
template <int AF32>
__global__ __launch_bounds__(256) void gemm_k(const void* __restrict__ Av,
                                              const uint16_t* __restrict__ B,
                                              const float* __restrict__ bias,
                                              uint16_t* __restrict__ C, int M, int N) {
    __shared__ uint16_t lA[128 * 40];
    __shared__ uint16_t lB[128 * 40];
    const int tid = threadIdx.x;
    const int m0 = blockIdx.y * 128, n0 = blockIdx.x * 128;
    const int srow = tid >> 1, skh = (tid & 1) * 16;
    const int lane = tid & 63, wid = tid >> 6;
    const int wm = wid >> 1, wn = wid & 1;
    const int fn = lane & 15, fq = lane >> 4;
    f32x4 acc[4][4];
#pragma unroll
    for (int a = 0; a < 4; a++)
#pragma unroll
        for (int b = 0; b < 4; b++) acc[a][b] = f32x4{0.f, 0.f, 0.f, 0.f};

    for (int kt = 0; kt < 32; kt++) {
        if (AF32) {
            const float* A = (const float*)Av + (size_t)(m0 + srow) * 1024 + kt * 32 + skh;
#pragma unroll
            for (int i = 0; i < 4; i++) {
                f32x4 t = *(const f32x4*)(A + i * 4);
                u16x4 p;
                p[0] = f2bf(t[0]); p[1] = f2bf(t[1]); p[2] = f2bf(t[2]); p[3] = f2bf(t[3]);
                *(u16x4*)&lA[srow * 40 + skh + i * 4] = p;
            }
        } else {
            const uint16_t* A = (const uint16_t*)Av + (size_t)(m0 + srow) * 1024 + kt * 32 + skh;
            *(u16x8*)&lA[srow * 40 + skh]     = *(const u16x8*)(A);
            *(u16x8*)&lA[srow * 40 + skh + 8] = *(const u16x8*)(A + 8);
        }
        const uint16_t* Bp = B + (size_t)(n0 + srow) * 1024 + kt * 32 + skh;
        *(u16x8*)&lB[srow * 40 + skh]     = *(const u16x8*)(Bp);
        *(u16x8*)&lB[srow * 40 + skh + 8] = *(const u16x8*)(Bp + 8);
        __syncthreads();
        s16x8 af[4], bfv[4];
#pragma unroll
        for (int mt = 0; mt < 4; mt++) af[mt] = *(const s16x8*)&lA[(wm * 64 + mt * 16 + fn) * 40 + fq * 8];
#pragma unroll
        for (int nt = 0; nt < 4; nt++) bfv[nt] = *(const s16x8*)&lB[(wn * 64 + nt * 16 + fn) * 40 + fq * 8];
#pragma unroll
        for (int mt = 0; mt < 4; mt++)
#pragma unroll
            for (int nt = 0; nt < 4; nt++)
                acc[mt][nt] = __builtin_amdgcn_mfma_f32_16x16x32_bf16(af[mt], bfv[nt], acc[mt][nt], 0, 0, 0);
        __syncthreads();
    }
#pragma unroll
    for (int nt = 0; nt < 4; nt++) {
        int col = n0 + wn * 64 + nt * 16 + fn;
        float bvv = bias ? bias[col] : 0.0f;
#pragma unroll
        for (int mt = 0; mt < 4; mt++) {
            int row0 = m0 + wm * 64 + mt * 16 + fq * 4;
#pragma unroll
            for (int i = 0; i < 4; i++)
                C[(size_t)(row0 + i) * N + col] = f2bf(acc[mt][nt][i] + bvv);
        }
    }
}

// ---------------------------------------------------------------------------
// LSTM recurrence, relaxed-agent-atomic edition (round-1 topology: 64 WGs,
// WG = (dir, 16-gate-slice j), one wave each; no XCD assumptions).
// ALL cross-CU traffic (h data + flags) uses relaxed AGENT-scope atomics,
// which on gfx950 compile to sc1-flagged global ops: line-granular coherent
// at the device coherence point, NO buffer_inv / buffer_wbl2 / threadfence.
// Release ordering = s_waitcnt vmcnt(0) (drain h stores) before flag store.
// hx layout: [dir][p][batch 16][256 x u32]   (u32 = 2 packed bf16 cols).
// hx doubles as the encoder output consumed by kpool.
// xs layout:  [dir][b*1024+p][2048] bf16 (gate order i,f,g,o).
// ctrl: [64..95]=dir0 flags; [128..159]=dir1 flags (per-WG step counters).
// ---------------------------------------------------------------------------
__global__ __launch_bounds__(64, 1) void krecur(const uint16_t* __restrict__ whhbf,
                                                const uint16_t* __restrict__ xs,
                                                uint32_t* __restrict__ hx,
                                                uint32_t* ctrl) {
    const int wg = blockIdx.x;
    const int dir = wg >> 5, j = wg & 31;
    const int lane = threadIdx.x;
    const int n = lane & 15, q = lane >> 4;

    s16x8 Bf[4][16];
    {
        const uint16_t* wb = whhbf + (size_t)dir * 2048 * 512;
#pragma unroll
        for (int t4 = 0; t4 < 4; t4++)
#pragma unroll
            for (int s = 0; s < 16; s++)
                Bf[t4][s] = *(const s16x8*)(wb + (size_t)(t4 * 512 + j * 16 + n) * 512 + s * 32 + q * 8);
    }
    float c[4] = {0.f, 0.f, 0.f, 0.f};
    const uint16_t* xsp = xs + (size_t)dir * 16384 * 2048;
    uint32_t* hxp = hx + (size_t)dir * 1024 * 16 * 256;
    uint32_t* flags  = ctrl + 64 + dir * 64;
    uint32_t* myflag = flags + j;
    uint32_t* pollp  = flags + (lane & 31);

    for (int t = 0; t < 1024; t++) {
        const int p = dir ? (1023 - t) : t;

        // prefetch xs for this step (independent of h): HBM latency hides
        // under the flag spin
        uint16_t xv[4][4];
#pragma unroll
        for (int t4 = 0; t4 < 4; t4++)
#pragma unroll
            for (int i = 0; i < 4; i++)
                xv[t4][i] = xsp[((size_t)(4 * q + i) * 1024 + p) * 2048 + t4 * 512 + j * 16 + n];

        f32x4 acc[4];
#pragma unroll
        for (int t4 = 0; t4 < 4; t4++) acc[t4] = f32x4{0.f, 0.f, 0.f, 0.f};

        if (t > 0) {
            const uint32_t tgt = (uint32_t)t;
            // wait until all 32 producer WGs have published step t
            for (;;) {
                uint32_t fv = __hip_atomic_load(pollp, __ATOMIC_RELAXED, __HIP_MEMORY_SCOPE_AGENT);
                if (__ballot(fv < tgt) == 0ull) break;
            }
            asm volatile("" ::: "memory");  // compiler barrier: no hoisting of h loads

            const int pp = dir ? (p + 1) : (p - 1);
            const unsigned long long* hrow =
                (const unsigned long long*)(hxp + ((size_t)pp * 16 + n) * 256);
            s16x8 Af[16];
#pragma unroll
            for (int s = 0; s < 16; s++) {
                unsigned long long lo = __hip_atomic_load(hrow + s * 8 + q * 2,
                                                          __ATOMIC_RELAXED, __HIP_MEMORY_SCOPE_AGENT);
                unsigned long long hi = __hip_atomic_load(hrow + s * 8 + q * 2 + 1,
                                                          __ATOMIC_RELAXED, __HIP_MEMORY_SCOPE_AGENT);
                union { struct { unsigned long long lo, hi; } u; s16x8 v; } cvt;
                cvt.u.lo = lo; cvt.u.hi = hi;
                Af[s] = cvt.v;
            }
#pragma unroll
            for (int s = 0; s < 16; s++) {
#pragma unroll
                for (int t4 = 0; t4 < 4; t4++)
                    acc[t4] = __builtin_amdgcn_mfma_f32_16x16x32_bf16(Af[s], Bf[t4][s], acc[t4], 0, 0, 0);
            }
        }

        float g4[4][4];
#pragma unroll
        for (int t4 = 0; t4 < 4; t4++)
#pragma unroll
            for (int i = 0; i < 4; i++)
                g4[t4][i] = acc[t4][i] + bf2f(xv[t4][i]);

#pragma unroll
        for (int i = 0; i < 4; i++) {
            float ig = sigm(g4[0][i]);
            float fg = sigm(g4[1][i]);
            float gg = tanh_f(g4[2][i]);
            float og = sigm(g4[3][i]);
            c[i] = fg * c[i] + ig * gg;
            float hv = og * tanh_f(c[i]);
            uint32_t mine = (uint32_t)f2bf(hv);
            uint32_t part = __shfl_xor(mine, 1);
            if ((n & 1) == 0) {
                uint32_t pack = mine | (part << 16);  // lo = even col
                __hip_atomic_store(hxp + ((size_t)p * 16 + 4 * q + i) * 256 + j * 8 + (n >> 1),
                                   pack, __ATOMIC_RELAXED, __HIP_MEMORY_SCOPE_AGENT);
            }
        }
        // release: drain h stores to the coherence point, then publish step
        asm volatile("s_waitcnt vmcnt(0)" ::: "memory");
        if (lane == 0)
            __hip_atomic_store(myflag, (uint32_t)(t + 1),
                               __ATOMIC_RELAXED, __HIP_MEMORY_SCOPE_AGENT);
    }
}

// ---------------------------------------------------------------------------
// Span mean-pool + LayerNorm1. One block per (b,s). Reads packed hx.
// ---------------------------------------------------------------------------
__global__ __launch_bounds__(256) void kpool(const uint32_t* __restrict__ hx,
                                             const int* __restrict__ heads,
                                             const int* __restrict__ tails,
                                             const float* __restrict__ g,
                                             const float* __restrict__ bb,
                                             float* __restrict__ feat,
                                             uint16_t* __restrict__ featb) {
    const int m = blockIdx.x;
    const int b = m >> 5;
    const int tid = threadIdx.x;
    const int h0 = tid * 4;
    const int dir = h0 >> 9, hid = h0 & 511;
    int p0 = heads[m] + 1; if (p0 < 0) p0 = 0;
    int p1 = tails[m];     if (p1 > 1024) p1 = 1024;
    float a0 = 0, a1 = 0, a2 = 0, a3 = 0;
    int cnt = p1 - p0; if (cnt < 1) cnt = 1;
    for (int p = p0; p < p1; p++) {
        const uint32_t* e = hx + (((size_t)dir * 1024 + p) * 16 + b) * 256 + (hid >> 1);
        uint32_t w0 = e[0], w1 = e[1];
        a0 += bf2f((uint16_t)(w0 & 0xffff)); a1 += bf2f((uint16_t)(w0 >> 16));
        a2 += bf2f((uint16_t)(w1 & 0xffff)); a3 += bf2f((uint16_t)(w1 >> 16));
    }
    float inv = 1.0f / (float)cnt;
    float x0 = a0 * inv, x1 = a1 * inv, x2 = a2 * inv, x3 = a3 * inv;
    float ls = x0 + x1 + x2 + x3;
    float lq = x0 * x0 + x1 * x1 + x2 * x2 + x3 * x3;
#pragma unroll
    for (int o = 32; o > 0; o >>= 1) { ls += __shfl_down(ls, o); lq += __shfl_down(lq, o); }
    __shared__ float rs_[4], rq_[4], st_[2];
    const int lane = tid & 63, wid = tid >> 6;
    if (lane == 0) { rs_[wid] = ls; rq_[wid] = lq; }
    __syncthreads();
    if (tid == 0) {
        float S = rs_[0] + rs_[1] + rs_[2] + rs_[3];
        float Q = rq_[0] + rq_[1] + rq_[2] + rq_[3];
        float mean = S * (1.0f / 1024.0f);
        float var = Q * (1.0f / 1024.0f) - mean * mean;
        st_[0] = mean;
        st_[1] = rsqrtf(var + 1e-7f);
    }
    __syncthreads();
    float mean = st_[0], rstd = st_[1];
    size_t ob = (size_t)m * 1024 + h0;
    float y0 = (x0 - mean) * rstd * g[h0 + 0] + bb[h0 + 0];
    float y1 = (x1 - mean) * rstd * g[h0 + 1] + bb[h0 + 1];
    float y2 = (x2 - mean) * rstd * g[h0 + 2] + bb[h0 + 2];
    float y3 = (x3 - mean) * rstd * g[h0 + 3] + bb[h0 + 3];
    feat[ob + 0] = y0; feat[ob + 1] = y1; feat[ob + 2] = y2; feat[ob + 3] = y3;
    featb[ob + 0] = f2bf(y0); featb[ob + 1] = f2bf(y1);
    featb[ob + 2] = f2bf(y2); featb[ob + 3] = f2bf(y3);
}

// ---------------------------------------------------------------------------
// Attention over S=32, per (b, head). One wave per block.
// ---------------------------------------------------------------------------
__global__ __launch_bounds__(64) void kattn(const uint16_t* __restrict__ qkv,
                                            const int* __restrict__ am,
                                            uint16_t* __restrict__ ctxb) {
    const int bb_ = blockIdx.x >> 4, nh = blockIdx.x & 15;
    const int lane = threadIdx.x;
    __shared__ float qs[32][65], ks[32][65], vs[32][65];
    __shared__ float ps[32][33];
    for (int s = 0; s < 32; s++) {
        const uint16_t* base = qkv + (size_t)(bb_ * 32 + s) * 3072 + nh * 64;
        qs[s][lane] = bf2f(base[lane]);
        ks[s][lane] = bf2f(base[1024 + lane]);
        vs[s][lane] = bf2f(base[2048 + lane]);
    }
    __syncthreads();
    const int r = lane >> 1, ch = (lane & 1) * 16;
    const int amr = am[bb_ * 32 + r];
    float sc[16];
#pragma unroll
    for (int c0 = 0; c0 < 16; c0++) {
        int cc = ch + c0;
        float a = 0;
        for (int d = 0; d < 64; d++) a += qs[r][d] * ks[cc][d];
        a *= 0.125f;
        if (!(amr && am[bb_ * 32 + cc])) a = -1e9f;
        sc[c0] = a;
    }
    float mx = sc[0];
#pragma unroll
    for (int c0 = 1; c0 < 16; c0++) mx = fmaxf(mx, sc[c0]);
    mx = fmaxf(mx, __shfl_xor(mx, 1));
    float se = 0;
#pragma unroll
    for (int c0 = 0; c0 < 16; c0++) { sc[c0] = __expf(sc[c0] - mx); se += sc[c0]; }
    se += __shfl_xor(se, 1);
    float inv = __builtin_amdgcn_rcpf(se);
#pragma unroll
    for (int c0 = 0; c0 < 16; c0++) ps[r][ch + c0] = sc[c0] * inv;
    __syncthreads();
    for (int r2 = 0; r2 < 32; r2++) {
        float a = 0;
        for (int cc = 0; cc < 32; cc++) a += ps[r2][cc] * vs[cc][lane];
        ctxb[(size_t)(bb_ * 32 + r2) * 1024 + nh * 64 + lane] = f2bf(a);
    }
}

// ---------------------------------------------------------------------------
// LN2 over (oproj + feat residual)
// ---------------------------------------------------------------------------
__global__ __launch_bounds__(256) void kln2(const uint16_t* __restrict__ oproj,
                                            const float* __restrict__ feat,
                                            const float* __restrict__ g,
                                            const float* __restrict__ bb,
                                            float* __restrict__ feat2) {
    const int m = blockIdx.x, tid = threadIdx.x;
    const int h0 = tid * 4;
    size_t base = (size_t)m * 1024 + h0;
    u16x4 ov = *(const u16x4*)(oproj + base);
    float x0 = bf2f(ov[0]) + feat[base + 0];
    float x1 = bf2f(ov[1]) + feat[base + 1];
    float x2 = bf2f(ov[2]) + feat[base + 2];
    float x3 = bf2f(ov[3]) + feat[base + 3];
    float ls = x0 + x1 + x2 + x3;
    float lq = x0 * x0 + x1 * x1 + x2 * x2 + x3 * x3;
#pragma unroll
    for (int o = 32; o > 0; o >>= 1) { ls += __shfl_down(ls, o); lq += __shfl_down(lq, o); }
    __shared__ float rs_[4], rq_[4], st_[2];
    const int lane = tid & 63, wid = tid >> 6;
    if (lane == 0) { rs_[wid] = ls; rq_[wid] = lq; }
    __syncthreads();
    if (tid == 0) {
        float S = rs_[0] + rs_[1] + rs_[2] + rs_[3];
        float Q = rq_[0] + rq_[1] + rq_[2] + rq_[3];
        float mean = S * (1.0f / 1024.0f);
        float var = Q * (1.0f / 1024.0f) - mean * mean;
        st_[0] = mean;
        st_[1] = rsqrtf(var + 1e-7f);
    }
    __syncthreads();
    float mean = st_[0], rstd = st_[1];
    feat2[base + 0] = (x0 - mean) * rstd * g[h0 + 0] + bb[h0 + 0];
    feat2[base + 1] = (x1 - mean) * rstd * g[h0 + 1] + bb[h0 + 1];
    feat2[base + 2] = (x2 - mean) * rstd * g[h0 + 2] + bb[h0 + 2];
    feat2[base + 3] = (x3 - mean) * rstd * g[h0 + 3] + bb[h0 + 3];
}

// ---------------------------------------------------------------------------
// Classifier + CE + focal. One wave per (b,s); atomic partials.
// ---------------------------------------------------------------------------
__global__ __launch_bounds__(64) void kloss(const float* __restrict__ feat2,
                                            const float* __restrict__ Wc,
                                            const float* __restrict__ bc,
                                            const int* __restrict__ labels,
                                            const int* __restrict__ am,
                                            const float* __restrict__ wf,
                                            float* __restrict__ accum) {
    const int m = blockIdx.x, lane = threadIdx.x;
    float l0 = 0, l1 = 0, l2 = 0;
    for (int k = lane; k < 1024; k += 64) {
        float f = feat2[(size_t)m * 1024 + k];
        l0 += f * Wc[k * 3 + 0];
        l1 += f * Wc[k * 3 + 1];
        l2 += f * Wc[k * 3 + 2];
    }
#pragma unroll
    for (int o = 32; o > 0; o >>= 1) {
        l0 += __shfl_down(l0, o);
        l1 += __shfl_down(l1, o);
        l2 += __shfl_down(l2, o);
    }
    if (lane == 0) {
        l0 += bc[0]; l1 += bc[1]; l2 += bc[2];
        float mx = fmaxf(l0, fmaxf(l1, l2));
        float e0 = __expf(l0 - mx), e1 = __expf(l1 - mx), e2 = __expf(l2 - mx);
        float lse = mx + __logf(e0 + e1 + e2);
        float lp[3] = {l0 - lse, l1 - lse, l2 - lse};
        int lab = labels[m];
        float validf = (lab >= 0) ? 1.0f : 0.0f;
        int labc = lab < 0 ? 0 : lab;
        float amv = (am[m] != 0) ? 1.0f : 0.0f;
        float spanm = amv * validf;
        float ce = -lp[labc] * wf[m];
        float pt = __expf(lp[labc]);
        float om = 1.0f - pt;
        float ft = -(om * om * lp[labc]);
        atomicAdd(accum + 0, ce * spanm);
        atomicAdd(accum + 1, spanm);
        atomicAdd(accum + 2, ft * validf);
        atomicAdd(accum + 3, validf);
    }
}

__global__ void kfinal(const float* __restrict__ accum, float* __restrict__ out) {
    out[0] = accum[0] / fmaxf(accum[1], 1.0f) + accum[2] / fmaxf(accum[3], 1.0f);
}

// ---------------------------------------------------------------------------
extern "C" void kernel_launch(void* const* d_in, const int* in_sizes, int n_in,
                              void* d_out, int out_size, void* d_ws, size_t ws_size,
                              hipStream_t stream) {
    const float* hs   = (const float*)d_in[0];
    const int* heads  = (const int*)d_in[1];
    const int* tails  = (const int*)d_in[2];
    const int* amask  = (const int*)d_in[3];
    const int* labels = (const int*)d_in[4];
    const float* wfac = (const float*)d_in[5];
    const float* wihf = (const float*)d_in[6];
    const float* whhf = (const float*)d_in[7];
    const float* lbf  = (const float*)d_in[8];
    const float* wihb = (const float*)d_in[9];
    const float* whhb = (const float*)d_in[10];
    const float* lbb  = (const float*)d_in[11];
    const float* ln1g = (const float*)d_in[12];
    const float* ln1b = (const float*)d_in[13];
    const float* Wq   = (const float*)d_in[14];
    const float* bq   = (const float*)d_in[15];
    const float* Wk   = (const float*)d_in[16];
    const float* bk   = (const float*)d_in[17];
    const float* Wv   = (const float*)d_in[18];
    const float* bv   = (const float*)d_in[19];
    const float* Wo   = (const float*)d_in[20];
    const float* bo   = (const float*)d_in[21];
    const float* ln2g = (const float*)d_in[22];
    const float* ln2b = (const float*)d_in[23];
    const float* Wc   = (const float*)d_in[24];
    const float* bc   = (const float*)d_in[25];

    char* ws = (char*)d_ws;
    uint32_t* ctrl  = (uint32_t*)(ws + 0);            // 4 KiB control block
    float* accum    = (float*)(ws + 1024);
    uint16_t* whhbf = (uint16_t*)(ws + 4096);
    uint16_t* wihbf = (uint16_t*)(ws + 4198400);
    uint16_t* wqkvo = (uint16_t*)(ws + 12587008);
    float* biasqkv  = (float*)(ws + 20975616);
    uint16_t* xs    = (uint16_t*)(ws + 20987904);
    uint32_t* hx    = (uint32_t*)(ws + 155205632);    // 33.55 MB packed h
    float* feat     = (float*)(ws + 188760064);
    uint16_t* featb = (uint16_t*)(ws + 190857216);
    uint16_t* qkvb  = (uint16_t*)(ws + 191905792);
    uint16_t* ctxb  = (uint16_t*)(ws + 195051520);
    uint16_t* oprojb= (uint16_t*)(ws + 196100096);
    float* feat2    = (float*)(ws + 197148672);       // end ~199.25 MB

    hipMemsetAsync(ws, 0, 4096, stream);  // flags + loss accumulators

    kprep<<<24588, 256, 0, stream>>>(wihf, wihb, whhf, whhb, bq, bk, bv, wihbf, whhbf, biasqkv);
    ktrans<<<dim3(32, 32, 4), dim3(32, 8), 0, stream>>>(Wq, Wk, Wv, Wo, wqkvo);

    gemm_k<1><<<dim3(16, 128), 256, 0, stream>>>(hs, wihbf, lbf, xs, 16384, 2048);
    gemm_k<1><<<dim3(16, 128), 256, 0, stream>>>(hs, wihbf + (size_t)2048 * 1024, lbb,
                                                 xs + (size_t)16384 * 2048, 16384, 2048);

    krecur<<<64, 64, 0, stream>>>(whhbf, xs, hx, ctrl);

    kpool<<<512, 256, 0, stream>>>(hx, heads, tails, ln1g, ln1b, feat, featb);

    gemm_k<0><<<dim3(24, 4), 256, 0, stream>>>(featb, wqkvo, biasqkv, qkvb, 512, 3072);

    kattn<<<256, 64, 0, stream>>>(qkvb, amask, ctxb);

    gemm_k<0><<<dim3(8, 4), 256, 0, stream>>>(ctxb, wqkvo + (size_t)3072 * 1024, bo, oprojb, 512, 1024);

    kln2<<<512, 256, 0, stream>>>(oprojb, feat, ln2g, ln2b, feat2);
    kloss<<<512, 64, 0, stream>>>(feat2, Wc, bc, labels, amask, wfac, accum);
    kfinal<<<1, 1, 0, stream>>>(accum, (float*)d_out);
}

// Round 4
// 3802.279 us; speedup vs baseline: 3.6009x; 1.7353x over previous
//
#include <hip/hip_runtime.h>
#include <stdint.h>

typedef __attribute__((ext_vector_type(4))) float    f32x4;
typedef __attribute__((ext_vector_type(8))) short    s16x8;
typedef __attribute__((ext_vector_type(4))) uint32_t u32x4;
typedef __attribute__((ext_vector_type(4))) uint16_t u16x4;
typedef __attribute__((ext_vector_type(8))) uint16_t u16x8;

#define SENT 0xFFFFFFFFu

__device__ __forceinline__ uint16_t f2bf(float f) {
    uint32_t u = __float_as_uint(f);
    u = u + 0x7FFFu + ((u >> 16) & 1u);
    return (uint16_t)(u >> 16);
}
__device__ __forceinline__ float bf2f(uint16_t h) {
    return __uint_as_float(((uint32_t)h) << 16);
}
__device__ __forceinline__ float sigm(float x) {
    return __builtin_amdgcn_rcpf(1.0f + __expf(-x));
}
__device__ __forceinline__ float tanh_f(float x) {
    float e = __expf(2.0f * x);
    return 1.0f - 2.0f * __builtin_amdgcn_rcpf(e + 1.0f);
}

// ---------------------------------------------------------------------------
// Sentinel-fill the h exchange buffer (bf16 NaN pairs).
// ---------------------------------------------------------------------------
__global__ void kinit(uint32_t* __restrict__ hx) {
    size_t i = ((size_t)blockIdx.x * 256 + threadIdx.x) * 4;
    *(u32x4*)(hx + i) = u32x4{SENT, SENT, SENT, SENT};
}

// ---------------------------------------------------------------------------
// Prep: cast Wih/Whh to bf16, build concat qkv bias
// ---------------------------------------------------------------------------
__global__ void kprep(const float* __restrict__ wihf, const float* __restrict__ wihb,
                      const float* __restrict__ whhf, const float* __restrict__ whhb,
                      const float* __restrict__ bq, const float* __restrict__ bk,
                      const float* __restrict__ bv,
                      uint16_t* __restrict__ wihbf, uint16_t* __restrict__ whhbf,
                      float* __restrict__ biasqkv) {
    size_t i = (size_t)blockIdx.x * 256 + threadIdx.x;
    if (i < 2097152) {
        wihbf[i] = f2bf(wihf[i]);
    } else if (i < 4194304) {
        wihbf[i] = f2bf(wihb[i - 2097152]);
    } else if (i < 5242880) {
        whhbf[i - 4194304] = f2bf(whhf[i - 4194304]);
    } else if (i < 6291456) {
        whhbf[i - 4194304] = f2bf(whhb[i - 5242880]);
    } else if (i < 6294528) {
        size_t k = i - 6291456;
        biasqkv[k] = (k < 1024) ? bq[k] : (k < 2048) ? bk[k - 1024] : bv[k - 2048];
    }
}

// transpose+cast Wq/Wk/Wv/Wo (1024x1024 f32 [k][n]) -> [z][n][k] bf16
__global__ void ktrans(const float* __restrict__ Wq, const float* __restrict__ Wk,
                       const float* __restrict__ Wv, const float* __restrict__ Wo,
                       uint16_t* __restrict__ out) {
    const float* W = (blockIdx.z == 0) ? Wq : (blockIdx.z == 1) ? Wk : (blockIdx.z == 2) ? Wv : Wo;
    __shared__ float t[32][33];
    int x  = blockIdx.x * 32 + threadIdx.x;
    int y0 = blockIdx.y * 32 + threadIdx.y;
#pragma unroll
    for (int i = 0; i < 4; i++)
        t[threadIdx.y + 8 * i][threadIdx.x] = W[(size_t)(y0 + 8 * i) * 1024 + x];
    __syncthreads();
    int ox  = blockIdx.y * 32 + threadIdx.x;
    int oy0 = blockIdx.x * 32 + threadIdx.y;
#pragma unroll
    for (int i = 0; i < 4; i++)
        out[((size_t)blockIdx.z * 1024 + oy0 + 8 * i) * 1024 + ox] = f2bf(t[threadIdx.x][threadIdx.y + 8 * i]);
}

// ---------------------------------------------------------------------------
// Generic bf16 MFMA GEMM: C[M][N] = A[M][1024] * B[N][1024]^T + bias, bf16 out.
// ---------------------------------------------------------------------------
template <int AF32>
__global__ __launch_bounds__(256) void gemm_k(const void* __restrict__ Av,
                                              const uint16_t* __restrict__ B,
                                              const float* __restrict__ bias,
                                              uint16_t* __restrict__ C, int M, int N) {
    __shared__ uint16_t lA[128 * 40];
    __shared__ uint16_t lB[128 * 40];
    const int tid = threadIdx.x;
    const int m0 = blockIdx.y * 128, n0 = blockIdx.x * 128;
    const int srow = tid >> 1, skh = (tid & 1) * 16;
    const int lane = tid & 63, wid = tid >> 6;
    const int wm = wid >> 1, wn = wid & 1;
    const int fn = lane & 15, fq = lane >> 4;
    f32x4 acc[4][4];
#pragma unroll
    for (int a = 0; a < 4; a++)
#pragma unroll
        for (int b = 0; b < 4; b++) acc[a][b] = f32x4{0.f, 0.f, 0.f, 0.f};

    for (int kt = 0; kt < 32; kt++) {
        if (AF32) {
            const float* A = (const float*)Av + (size_t)(m0 + srow) * 1024 + kt * 32 + skh;
#pragma unroll
            for (int i = 0; i < 4; i++) {
                f32x4 t = *(const f32x4*)(A + i * 4);
                u16x4 p;
                p[0] = f2bf(t[0]); p[1] = f2bf(t[1]); p[2] = f2bf(t[2]); p[3] = f2bf(t[3]);
                *(u16x4*)&lA[srow * 40 + skh + i * 4] = p;
            }
        } else {
            const uint16_t* A = (const uint16_t*)Av + (size_t)(m0 + srow) * 1024 + kt * 32 + skh;
            *(u16x8*)&lA[srow * 40 + skh]     = *(const u16x8*)(A);
            *(u16x8*)&lA[srow * 40 + skh + 8] = *(const u16x8*)(A + 8);
        }
        const uint16_t* Bp = B + (size_t)(n0 + srow) * 1024 + kt * 32 + skh;
        *(u16x8*)&lB[srow * 40 + skh]     = *(const u16x8*)(Bp);
        *(u16x8*)&lB[srow * 40 + skh + 8] = *(const u16x8*)(Bp + 8);
        __syncthreads();
        s16x8 af[4], bfv[4];
#pragma unroll
        for (int mt = 0; mt < 4; mt++) af[mt] = *(const s16x8*)&lA[(wm * 64 + mt * 16 + fn) * 40 + fq * 8];
#pragma unroll
        for (int nt = 0; nt < 4; nt++) bfv[nt] = *(const s16x8*)&lB[(wn * 64 + nt * 16 + fn) * 40 + fq * 8];
#pragma unroll
        for (int mt = 0; mt < 4; mt++)
#pragma unroll
            for (int nt = 0; nt < 4; nt++)
                acc[mt][nt] = __builtin_amdgcn_mfma_f32_16x16x32_bf16(af[mt], bfv[nt], acc[mt][nt], 0, 0, 0);
        __syncthreads();
    }
#pragma unroll
    for (int nt = 0; nt < 4; nt++) {
        int col = n0 + wn * 64 + nt * 16 + fn;
        float bvv = bias ? bias[col] : 0.0f;
#pragma unroll
        for (int mt = 0; mt < 4; mt++) {
            int row0 = m0 + wm * 64 + mt * 16 + fq * 4;
#pragma unroll
            for (int i = 0; i < 4; i++)
                C[(size_t)(row0 + i) * N + col] = f2bf(acc[mt][nt][i] + bvv);
        }
    }
}

// ---------------------------------------------------------------------------
// LSTM recurrence, data-flow (sentinel) edition. 64 WGs x 1 wave,
// WG = (dir, 16-gate-slice j). Whh slice resident in VGPRs as MFMA B-frags.
// NO flags, NO store drains: h lines are written exactly once per step at
// fresh addresses (indexed by p); hx is pre-filled with 0xFFFFFFFF (bf16 NaN
// pairs, unreachable by tanh outputs), so consumers poll the data itself via
// agent-coherent (sc1) dwordx4 loads and retry while any word is sentinel.
// hx layout: [dir][p][batch 16][256 x u32]   (u32 = 2 packed bf16 cols).
// xs layout: [dir][b*1024+p][2048] bf16 (gate order i,f,g,o).
// ---------------------------------------------------------------------------
__global__ __launch_bounds__(64, 1) void krecur(const uint16_t* __restrict__ whhbf,
                                                const uint16_t* __restrict__ xs,
                                                uint32_t* __restrict__ hx) {
    const int wg = blockIdx.x;
    const int dir = wg >> 5, j = wg & 31;
    const int lane = threadIdx.x;
    const int n = lane & 15, q = lane >> 4;

    s16x8 Bf[4][16];
    {
        const uint16_t* wb = whhbf + (size_t)dir * 2048 * 512;
#pragma unroll
        for (int t4 = 0; t4 < 4; t4++)
#pragma unroll
            for (int s = 0; s < 16; s++)
                Bf[t4][s] = *(const s16x8*)(wb + (size_t)(t4 * 512 + j * 16 + n) * 512 + s * 32 + q * 8);
    }
    float c[4] = {0.f, 0.f, 0.f, 0.f};
    const uint16_t* xsp = xs + (size_t)dir * 16384 * 2048;
    uint32_t* hxp = hx + (size_t)dir * 1024 * 16 * 256;

    for (int t = 0; t < 1024; t++) {
        const int p = dir ? (1023 - t) : t;

        // prefetch xs for this step (independent of h): latency hides under
        // the data poll
        uint16_t xv[4][4];
#pragma unroll
        for (int t4 = 0; t4 < 4; t4++)
#pragma unroll
            for (int i = 0; i < 4; i++)
                xv[t4][i] = xsp[((size_t)(4 * q + i) * 1024 + p) * 2048 + t4 * 512 + j * 16 + n];

        f32x4 acc[4];
#pragma unroll
        for (int t4 = 0; t4 < 4; t4++) acc[t4] = f32x4{0.f, 0.f, 0.f, 0.f};

        if (t > 0) {
            const int pp = dir ? (p + 1) : (p - 1);
            const uint32_t* hrow = hxp + ((size_t)pp * 16 + n) * 256;
            u32x4 Ah[16];
            for (;;) {
#pragma unroll
                for (int s = 0; s < 16; s++) {
                    const uint32_t* ap = hrow + s * 16 + q * 4;
                    asm volatile("global_load_dwordx4 %0, %1, off sc1"
                                 : "=v"(Ah[s]) : "v"(ap) : "memory");
                }
                asm volatile("s_waitcnt vmcnt(0)" ::: "memory");
                uint32_t mx = 0;
#pragma unroll
                for (int s = 0; s < 16; s++) {
#pragma unroll
                    for (int w = 0; w < 4; w++) mx = (Ah[s][w] > mx) ? Ah[s][w] : mx;
                }
                if (__ballot(mx == SENT) == 0ull) break;
            }
#pragma unroll
            for (int s = 0; s < 16; s++) {
                s16x8 Af = __builtin_bit_cast(s16x8, Ah[s]);
#pragma unroll
                for (int t4 = 0; t4 < 4; t4++)
                    acc[t4] = __builtin_amdgcn_mfma_f32_16x16x32_bf16(Af, Bf[t4][s], acc[t4], 0, 0, 0);
            }
        }

        float g4[4][4];
#pragma unroll
        for (int t4 = 0; t4 < 4; t4++)
#pragma unroll
            for (int i = 0; i < 4; i++)
                g4[t4][i] = acc[t4][i] + bf2f(xv[t4][i]);

#pragma unroll
        for (int i = 0; i < 4; i++) {
            float ig = sigm(g4[0][i]);
            float fg = sigm(g4[1][i]);
            float gg = tanh_f(g4[2][i]);
            float og = sigm(g4[3][i]);
            c[i] = fg * c[i] + ig * gg;
            float hv = og * tanh_f(c[i]);
            uint32_t mine = (uint32_t)f2bf(hv);
            uint32_t part = __shfl_xor(mine, 1);
            if ((n & 1) == 0) {
                uint32_t pack = mine | (part << 16);  // lo = even col
                __hip_atomic_store(hxp + ((size_t)p * 16 + 4 * q + i) * 256 + j * 8 + (n >> 1),
                                   pack, __ATOMIC_RELAXED, __HIP_MEMORY_SCOPE_AGENT);
            }
        }
        // no drain, no flag: stores fly to the coherence point on their own;
        // consumers detect them by value.
    }
}

// ---------------------------------------------------------------------------
// Span mean-pool + LayerNorm1. One block per (b,s). Reads packed hx.
// ---------------------------------------------------------------------------
__global__ __launch_bounds__(256) void kpool(const uint32_t* __restrict__ hx,
                                             const int* __restrict__ heads,
                                             const int* __restrict__ tails,
                                             const float* __restrict__ g,
                                             const float* __restrict__ bb,
                                             float* __restrict__ feat,
                                             uint16_t* __restrict__ featb) {
    const int m = blockIdx.x;
    const int b = m >> 5;
    const int tid = threadIdx.x;
    const int h0 = tid * 4;
    const int dir = h0 >> 9, hid = h0 & 511;
    int p0 = heads[m] + 1; if (p0 < 0) p0 = 0;
    int p1 = tails[m];     if (p1 > 1024) p1 = 1024;
    float a0 = 0, a1 = 0, a2 = 0, a3 = 0;
    int cnt = p1 - p0; if (cnt < 1) cnt = 1;
    for (int p = p0; p < p1; p++) {
        const uint32_t* e = hx + (((size_t)dir * 1024 + p) * 16 + b) * 256 + (hid >> 1);
        uint32_t w0 = e[0], w1 = e[1];
        a0 += bf2f((uint16_t)(w0 & 0xffff)); a1 += bf2f((uint16_t)(w0 >> 16));
        a2 += bf2f((uint16_t)(w1 & 0xffff)); a3 += bf2f((uint16_t)(w1 >> 16));
    }
    float inv = 1.0f / (float)cnt;
    float x0 = a0 * inv, x1 = a1 * inv, x2 = a2 * inv, x3 = a3 * inv;
    float ls = x0 + x1 + x2 + x3;
    float lq = x0 * x0 + x1 * x1 + x2 * x2 + x3 * x3;
#pragma unroll
    for (int o = 32; o > 0; o >>= 1) { ls += __shfl_down(ls, o); lq += __shfl_down(lq, o); }
    __shared__ float rs_[4], rq_[4], st_[2];
    const int lane = tid & 63, wid = tid >> 6;
    if (lane == 0) { rs_[wid] = ls; rq_[wid] = lq; }
    __syncthreads();
    if (tid == 0) {
        float S = rs_[0] + rs_[1] + rs_[2] + rs_[3];
        float Q = rq_[0] + rq_[1] + rq_[2] + rq_[3];
        float mean = S * (1.0f / 1024.0f);
        float var = Q * (1.0f / 1024.0f) - mean * mean;
        st_[0] = mean;
        st_[1] = rsqrtf(var + 1e-7f);
    }
    __syncthreads();
    float mean = st_[0], rstd = st_[1];
    size_t ob = (size_t)m * 1024 + h0;
    float y0 = (x0 - mean) * rstd * g[h0 + 0] + bb[h0 + 0];
    float y1 = (x1 - mean) * rstd * g[h0 + 1] + bb[h0 + 1];
    float y2 = (x2 - mean) * rstd * g[h0 + 2] + bb[h0 + 2];
    float y3 = (x3 - mean) * rstd * g[h0 + 3] + bb[h0 + 3];
    feat[ob + 0] = y0; feat[ob + 1] = y1; feat[ob + 2] = y2; feat[ob + 3] = y3;
    featb[ob + 0] = f2bf(y0); featb[ob + 1] = f2bf(y1);
    featb[ob + 2] = f2bf(y2); featb[ob + 3] = f2bf(y3);
}

// ---------------------------------------------------------------------------
// Attention over S=32, per (b, head). One wave per block.
// ---------------------------------------------------------------------------
__global__ __launch_bounds__(64) void kattn(const uint16_t* __restrict__ qkv,
                                            const int* __restrict__ am,
                                            uint16_t* __restrict__ ctxb) {
    const int bb_ = blockIdx.x >> 4, nh = blockIdx.x & 15;
    const int lane = threadIdx.x;
    __shared__ float qs[32][65], ks[32][65], vs[32][65];
    __shared__ float ps[32][33];
    for (int s = 0; s < 32; s++) {
        const uint16_t* base = qkv + (size_t)(bb_ * 32 + s) * 3072 + nh * 64;
        qs[s][lane] = bf2f(base[lane]);
        ks[s][lane] = bf2f(base[1024 + lane]);
        vs[s][lane] = bf2f(base[2048 + lane]);
    }
    __syncthreads();
    const int r = lane >> 1, ch = (lane & 1) * 16;
    const int amr = am[bb_ * 32 + r];
    float sc[16];
#pragma unroll
    for (int c0 = 0; c0 < 16; c0++) {
        int cc = ch + c0;
        float a = 0;
        for (int d = 0; d < 64; d++) a += qs[r][d] * ks[cc][d];
        a *= 0.125f;
        if (!(amr && am[bb_ * 32 + cc])) a = -1e9f;
        sc[c0] = a;
    }
    float mx = sc[0];
#pragma unroll
    for (int c0 = 1; c0 < 16; c0++) mx = fmaxf(mx, sc[c0]);
    mx = fmaxf(mx, __shfl_xor(mx, 1));
    float se = 0;
#pragma unroll
    for (int c0 = 0; c0 < 16; c0++) { sc[c0] = __expf(sc[c0] - mx); se += sc[c0]; }
    se += __shfl_xor(se, 1);
    float inv = __builtin_amdgcn_rcpf(se);
#pragma unroll
    for (int c0 = 0; c0 < 16; c0++) ps[r][ch + c0] = sc[c0] * inv;
    __syncthreads();
    for (int r2 = 0; r2 < 32; r2++) {
        float a = 0;
        for (int cc = 0; cc < 32; cc++) a += ps[r2][cc] * vs[cc][lane];
        ctxb[(size_t)(bb_ * 32 + r2) * 1024 + nh * 64 + lane] = f2bf(a);
    }
}

// ---------------------------------------------------------------------------
// LN2 over (oproj + feat residual)
// ---------------------------------------------------------------------------
__global__ __launch_bounds__(256) void kln2(const uint16_t* __restrict__ oproj,
                                            const float* __restrict__ feat,
                                            const float* __restrict__ g,
                                            const float* __restrict__ bb,
                                            float* __restrict__ feat2) {
    const int m = blockIdx.x, tid = threadIdx.x;
    const int h0 = tid * 4;
    size_t base = (size_t)m * 1024 + h0;
    u16x4 ov = *(const u16x4*)(oproj + base);
    float x0 = bf2f(ov[0]) + feat[base + 0];
    float x1 = bf2f(ov[1]) + feat[base + 1];
    float x2 = bf2f(ov[2]) + feat[base + 2];
    float x3 = bf2f(ov[3]) + feat[base + 3];
    float ls = x0 + x1 + x2 + x3;
    float lq = x0 * x0 + x1 * x1 + x2 * x2 + x3 * x3;
#pragma unroll
    for (int o = 32; o > 0; o >>= 1) { ls += __shfl_down(ls, o); lq += __shfl_down(lq, o); }
    __shared__ float rs_[4], rq_[4], st_[2];
    const int lane = tid & 63, wid = tid >> 6;
    if (lane == 0) { rs_[wid] = ls; rq_[wid] = lq; }
    __syncthreads();
    if (tid == 0) {
        float S = rs_[0] + rs_[1] + rs_[2] + rs_[3];
        float Q = rq_[0] + rq_[1] + rq_[2] + rq_[3];
        float mean = S * (1.0f / 1024.0f);
        float var = Q * (1.0f / 1024.0f) - mean * mean;
        st_[0] = mean;
        st_[1] = rsqrtf(var + 1e-7f);
    }
    __syncthreads();
    float mean = st_[0], rstd = st_[1];
    feat2[base + 0] = (x0 - mean) * rstd * g[h0 + 0] + bb[h0 + 0];
    feat2[base + 1] = (x1 - mean) * rstd * g[h0 + 1] + bb[h0 + 1];
    feat2[base + 2] = (x2 - mean) * rstd * g[h0 + 2] + bb[h0 + 2];
    feat2[base + 3] = (x3 - mean) * rstd * g[h0 + 3] + bb[h0 + 3];
}

// ---------------------------------------------------------------------------
// Classifier + CE + focal. One wave per (b,s); atomic partials.
// ---------------------------------------------------------------------------
__global__ __launch_bounds__(64) void kloss(const float* __restrict__ feat2,
                                            const float* __restrict__ Wc,
                                            const float* __restrict__ bc,
                                            const int* __restrict__ labels,
                                            const int* __restrict__ am,
                                            const float* __restrict__ wf,
                                            float* __restrict__ accum) {
    const int m = blockIdx.x, lane = threadIdx.x;
    float l0 = 0, l1 = 0, l2 = 0;
    for (int k = lane; k < 1024; k += 64) {
        float f = feat2[(size_t)m * 1024 + k];
        l0 += f * Wc[k * 3 + 0];
        l1 += f * Wc[k * 3 + 1];
        l2 += f * Wc[k * 3 + 2];
    }
#pragma unroll
    for (int o = 32; o > 0; o >>= 1) {
        l0 += __shfl_down(l0, o);
        l1 += __shfl_down(l1, o);
        l2 += __shfl_down(l2, o);
    }
    if (lane == 0) {
        l0 += bc[0]; l1 += bc[1]; l2 += bc[2];
        float mx = fmaxf(l0, fmaxf(l1, l2));
        float e0 = __expf(l0 - mx), e1 = __expf(l1 - mx), e2 = __expf(l2 - mx);
        float lse = mx + __logf(e0 + e1 + e2);
        float lp[3] = {l0 - lse, l1 - lse, l2 - lse};
        int lab = labels[m];
        float validf = (lab >= 0) ? 1.0f : 0.0f;
        int labc = lab < 0 ? 0 : lab;
        float amv = (am[m] != 0) ? 1.0f : 0.0f;
        float spanm = amv * validf;
        float ce = -lp[labc] * wf[m];
        float pt = __expf(lp[labc]);
        float om = 1.0f - pt;
        float ft = -(om * om * lp[labc]);
        atomicAdd(accum + 0, ce * spanm);
        atomicAdd(accum + 1, spanm);
        atomicAdd(accum + 2, ft * validf);
        atomicAdd(accum + 3, validf);
    }
}

__global__ void kfinal(const float* __restrict__ accum, float* __restrict__ out) {
    out[0] = accum[0] / fmaxf(accum[1], 1.0f) + accum[2] / fmaxf(accum[3], 1.0f);
}

// ---------------------------------------------------------------------------
extern "C" void kernel_launch(void* const* d_in, const int* in_sizes, int n_in,
                              void* d_out, int out_size, void* d_ws, size_t ws_size,
                              hipStream_t stream) {
    const float* hs   = (const float*)d_in[0];
    const int* heads  = (const int*)d_in[1];
    const int* tails  = (const int*)d_in[2];
    const int* amask  = (const int*)d_in[3];
    const int* labels = (const int*)d_in[4];
    const float* wfac = (const float*)d_in[5];
    const float* wihf = (const float*)d_in[6];
    const float* whhf = (const float*)d_in[7];
    const float* lbf  = (const float*)d_in[8];
    const float* wihb = (const float*)d_in[9];
    const float* whhb = (const float*)d_in[10];
    const float* lbb  = (const float*)d_in[11];
    const float* ln1g = (const float*)d_in[12];
    const float* ln1b = (const float*)d_in[13];
    const float* Wq   = (const float*)d_in[14];
    const float* bq   = (const float*)d_in[15];
    const float* Wk   = (const float*)d_in[16];
    const float* bk   = (const float*)d_in[17];
    const float* Wv   = (const float*)d_in[18];
    const float* bv   = (const float*)d_in[19];
    const float* Wo   = (const float*)d_in[20];
    const float* bo   = (const float*)d_in[21];
    const float* ln2g = (const float*)d_in[22];
    const float* ln2b = (const float*)d_in[23];
    const float* Wc   = (const float*)d_in[24];
    const float* bc   = (const float*)d_in[25];

    char* ws = (char*)d_ws;
    float* accum    = (float*)(ws + 1024);
    uint16_t* whhbf = (uint16_t*)(ws + 4096);
    uint16_t* wihbf = (uint16_t*)(ws + 4198400);
    uint16_t* wqkvo = (uint16_t*)(ws + 12587008);
    float* biasqkv  = (float*)(ws + 20975616);
    uint16_t* xs    = (uint16_t*)(ws + 20987904);
    uint32_t* hx    = (uint32_t*)(ws + 155205632);    // 33.55 MB packed h
    float* feat     = (float*)(ws + 188760064);
    uint16_t* featb = (uint16_t*)(ws + 190857216);
    uint16_t* qkvb  = (uint16_t*)(ws + 191905792);
    uint16_t* ctxb  = (uint16_t*)(ws + 195051520);
    uint16_t* oprojb= (uint16_t*)(ws + 196100096);
    float* feat2    = (float*)(ws + 197148672);       // end ~199.25 MB

    hipMemsetAsync(ws, 0, 4096, stream);  // loss accumulators

    kinit<<<8192, 256, 0, stream>>>(hx);  // sentinel-fill h exchange buffer

    kprep<<<24588, 256, 0, stream>>>(wihf, wihb, whhf, whhb, bq, bk, bv, wihbf, whhbf, biasqkv);
    ktrans<<<dim3(32, 32, 4), dim3(32, 8), 0, stream>>>(Wq, Wk, Wv, Wo, wqkvo);

    gemm_k<1><<<dim3(16, 128), 256, 0, stream>>>(hs, wihbf, lbf, xs, 16384, 2048);
    gemm_k<1><<<dim3(16, 128), 256, 0, stream>>>(hs, wihbf + (size_t)2048 * 1024, lbb,
                                                 xs + (size_t)16384 * 2048, 16384, 2048);

    krecur<<<64, 64, 0, stream>>>(whhbf, xs, hx);

    kpool<<<512, 256, 0, stream>>>(hx, heads, tails, ln1g, ln1b, feat, featb);

    gemm_k<0><<<dim3(24, 4), 256, 0, stream>>>(featb, wqkvo, biasqkv, qkvb, 512, 3072);

    kattn<<<256, 64, 0, stream>>>(qkvb, amask, ctxb);

    gemm_k<0><<<dim3(8, 4), 256, 0, stream>>>(ctxb, wqkvo + (size_t)3072 * 1024, bo, oprojb, 512, 1024);

    kln2<<<512, 256, 0, stream>>>(oprojb, feat, ln2g, ln2b, feat2);
    kloss<<<512, 64, 0, stream>>>(feat2, Wc, bc, labels, amask, wfac, accum);
    kfinal<<<1, 1, 0, stream>>>(accum, (float*)d_out);
}

// Round 5
// 3525.224 us; speedup vs baseline: 3.8839x; 1.0786x over previous
//
#include <hip/hip_runtime.h>
#include <stdint.h>

typedef __attribute__((ext_vector_type(4))) float    f32x4;
typedef __attribute__((ext_vector_type(8))) short    s16x8;
typedef __attribute__((ext_vector_type(4))) uint32_t u32x4;
typedef __attribute__((ext_vector_type(4))) uint16_t u16x4;
typedef __attribute__((ext_vector_type(8))) uint16_t u16x8;

#define SENT 0xFFFFFFFFu

__device__ __forceinline__ uint16_t f2bf(float f) {
    uint32_t u = __float_as_uint(f);
    u = u + 0x7FFFu + ((u >> 16) & 1u);
    return (uint16_t)(u >> 16);
}
__device__ __forceinline__ float bf2f(uint16_t h) {
    return __uint_as_float(((uint32_t)h) << 16);
}
__device__ __forceinline__ float sigm(float x) {
    return __builtin_amdgcn_rcpf(1.0f + __expf(-x));
}
__device__ __forceinline__ float tanh_f(float x) {
    float e = __expf(2.0f * x);
    return 1.0f - 2.0f * __builtin_amdgcn_rcpf(e + 1.0f);
}

// ---------------------------------------------------------------------------
// Sentinel-fill the h exchange buffer (bf16 NaN pairs).
// ---------------------------------------------------------------------------
__global__ void kinit(uint32_t* __restrict__ hx) {
    size_t i = ((size_t)blockIdx.x * 256 + threadIdx.x) * 4;
    *(u32x4*)(hx + i) = u32x4{SENT, SENT, SENT, SENT};
}

// ---------------------------------------------------------------------------
// Prep: cast Wih/Whh to bf16, build concat qkv bias
// ---------------------------------------------------------------------------
__global__ void kprep(const float* __restrict__ wihf, const float* __restrict__ wihb,
                      const float* __restrict__ whhf, const float* __restrict__ whhb,
                      const float* __restrict__ bq, const float* __restrict__ bk,
                      const float* __restrict__ bv,
                      uint16_t* __restrict__ wihbf, uint16_t* __restrict__ whhbf,
                      float* __restrict__ biasqkv) {
    size_t i = (size_t)blockIdx.x * 256 + threadIdx.x;
    if (i < 2097152) {
        wihbf[i] = f2bf(wihf[i]);
    } else if (i < 4194304) {
        wihbf[i] = f2bf(wihb[i - 2097152]);
    } else if (i < 5242880) {
        whhbf[i - 4194304] = f2bf(whhf[i - 4194304]);
    } else if (i < 6291456) {
        whhbf[i - 4194304] = f2bf(whhb[i - 5242880]);
    } else if (i < 6294528) {
        size_t k = i - 6291456;
        biasqkv[k] = (k < 1024) ? bq[k] : (k < 2048) ? bk[k - 1024] : bv[k - 2048];
    }
}

// transpose+cast Wq/Wk/Wv/Wo (1024x1024 f32 [k][n]) -> [z][n][k] bf16
__global__ void ktrans(const float* __restrict__ Wq, const float* __restrict__ Wk,
                       const float* __restrict__ Wv, const float* __restrict__ Wo,
                       uint16_t* __restrict__ out) {
    const float* W = (blockIdx.z == 0) ? Wq : (blockIdx.z == 1) ? Wk : (blockIdx.z == 2) ? Wv : Wo;
    __shared__ float t[32][33];
    int x  = blockIdx.x * 32 + threadIdx.x;
    int y0 = blockIdx.y * 32 + threadIdx.y;
#pragma unroll
    for (int i = 0; i < 4; i++)
        t[threadIdx.y + 8 * i][threadIdx.x] = W[(size_t)(y0 + 8 * i) * 1024 + x];
    __syncthreads();
    int ox  = blockIdx.y * 32 + threadIdx.x;
    int oy0 = blockIdx.x * 32 + threadIdx.y;
#pragma unroll
    for (int i = 0; i < 4; i++)
        out[((size_t)blockIdx.z * 1024 + oy0 + 8 * i) * 1024 + ox] = f2bf(t[threadIdx.x][threadIdx.y + 8 * i]);
}

// ---------------------------------------------------------------------------
// Generic bf16 MFMA GEMM: C[M][N] = A[M][1024] * B[N][1024]^T + bias, bf16 out.
// ---------------------------------------------------------------------------
template <int AF32>
__global__ __launch_bounds__(256) void gemm_k(const void* __restrict__ Av,
                                              const uint16_t* __restrict__ B,
                                              const float* __restrict__ bias,
                                              uint16_t* __restrict__ C, int M, int N) {
    __shared__ uint16_t lA[128 * 40];
    __shared__ uint16_t lB[128 * 40];
    const int tid = threadIdx.x;
    const int m0 = blockIdx.y * 128, n0 = blockIdx.x * 128;
    const int srow = tid >> 1, skh = (tid & 1) * 16;
    const int lane = tid & 63, wid = tid >> 6;
    const int wm = wid >> 1, wn = wid & 1;
    const int fn = lane & 15, fq = lane >> 4;
    f32x4 acc[4][4];
#pragma unroll
    for (int a = 0; a < 4; a++)
#pragma unroll
        for (int b = 0; b < 4; b++) acc[a][b] = f32x4{0.f, 0.f, 0.f, 0.f};

    for (int kt = 0; kt < 32; kt++) {
        if (AF32) {
            const float* A = (const float*)Av + (size_t)(m0 + srow) * 1024 + kt * 32 + skh;
#pragma unroll
            for (int i = 0; i < 4; i++) {
                f32x4 t = *(const f32x4*)(A + i * 4);
                u16x4 p;
                p[0] = f2bf(t[0]); p[1] = f2bf(t[1]); p[2] = f2bf(t[2]); p[3] = f2bf(t[3]);
                *(u16x4*)&lA[srow * 40 + skh + i * 4] = p;
            }
        } else {
            const uint16_t* A = (const uint16_t*)Av + (size_t)(m0 + srow) * 1024 + kt * 32 + skh;
            *(u16x8*)&lA[srow * 40 + skh]     = *(const u16x8*)(A);
            *(u16x8*)&lA[srow * 40 + skh + 8] = *(const u16x8*)(A + 8);
        }
        const uint16_t* Bp = B + (size_t)(n0 + srow) * 1024 + kt * 32 + skh;
        *(u16x8*)&lB[srow * 40 + skh]     = *(const u16x8*)(Bp);
        *(u16x8*)&lB[srow * 40 + skh + 8] = *(const u16x8*)(Bp + 8);
        __syncthreads();
        s16x8 af[4], bfv[4];
#pragma unroll
        for (int mt = 0; mt < 4; mt++) af[mt] = *(const s16x8*)&lA[(wm * 64 + mt * 16 + fn) * 40 + fq * 8];
#pragma unroll
        for (int nt = 0; nt < 4; nt++) bfv[nt] = *(const s16x8*)&lB[(wn * 64 + nt * 16 + fn) * 40 + fq * 8];
#pragma unroll
        for (int mt = 0; mt < 4; mt++)
#pragma unroll
            for (int nt = 0; nt < 4; nt++)
                acc[mt][nt] = __builtin_amdgcn_mfma_f32_16x16x32_bf16(af[mt], bfv[nt], acc[mt][nt], 0, 0, 0);
        __syncthreads();
    }
#pragma unroll
    for (int nt = 0; nt < 4; nt++) {
        int col = n0 + wn * 64 + nt * 16 + fn;
        float bvv = bias ? bias[col] : 0.0f;
#pragma unroll
        for (int mt = 0; mt < 4; mt++) {
            int row0 = m0 + wm * 64 + mt * 16 + fq * 4;
#pragma unroll
            for (int i = 0; i < 4; i++)
                C[(size_t)(row0 + i) * N + col] = f2bf(acc[mt][nt][i] + bvv);
        }
    }
}

// ---------------------------------------------------------------------------
// LSTM recurrence, multi-wave shared-poll edition.
// 16 WGs x 256 thr (4 waves). WG = (dir, g); wave w owns hidden slice
// j = g*4+w (64 gates, Whh B-frags resident in 256 VGPRs, same as before).
// Per step each wave polls only ITS quarter of h_{t-1} (4 x dwordx4 sc1,
// sentinel-detected), deposits it in LDS chunks; __syncthreads; all waves
// ds_read_b128 the full 16 A-fragments. LDS double-buffered by t-parity so
// one barrier per step suffices. Sentinel dataflow: hx pre-filled with
// 0xFFFFFFFF (bf16 NaN pairs, unreachable by tanh), every u32 written
// exactly once per step at a fresh (p-indexed) address.
// hx layout: [dir][p][batch 16][256 x u32]   (u32 = 2 packed bf16 cols).
// xs layout: [dir][b*1024+p][2048] bf16 (gate order i,f,g,o).
// LDS chunk(s,q,n) = 16B of h[batch n][k=s*32+q*8..+7]; dword-bank = 4n%32
// -> 2-way conflict only (free, m136).
// ---------------------------------------------------------------------------
__global__ __launch_bounds__(256, 1) void krecur(const uint16_t* __restrict__ whhbf,
                                                 const uint16_t* __restrict__ xs,
                                                 uint32_t* __restrict__ hx) {
    const int wg = blockIdx.x;           // 0..15
    const int dir = wg >> 3, g = wg & 7;
    const int tid = threadIdx.x;
    const int w = tid >> 6, lane = tid & 63;
    const int j = g * 4 + w;             // hidden slice 0..31
    const int n = lane & 15, q = lane >> 4;

    __shared__ uint16_t lh[2][8192];     // 2 x 16 KB

    s16x8 Bf[4][16];
    {
        const uint16_t* wb = whhbf + (size_t)dir * 2048 * 512;
#pragma unroll
        for (int t4 = 0; t4 < 4; t4++)
#pragma unroll
            for (int s = 0; s < 16; s++)
                Bf[t4][s] = *(const s16x8*)(wb + (size_t)(t4 * 512 + j * 16 + n) * 512 + s * 32 + q * 8);
    }
    float c[4] = {0.f, 0.f, 0.f, 0.f};
    const uint16_t* xsp = xs + (size_t)dir * 16384 * 2048;
    uint32_t* hxp = hx + (size_t)dir * 1024 * 4096;

    for (int t = 0; t < 1024; t++) {
        const int p = dir ? (1023 - t) : t;
        const int buf = t & 1;

        // prefetch xs for this step (independent of h): overlaps the poll
        uint16_t xv[4][4];
#pragma unroll
        for (int t4 = 0; t4 < 4; t4++)
#pragma unroll
            for (int i = 0; i < 4; i++)
                xv[t4][i] = xsp[((size_t)(4 * q + i) * 1024 + p) * 2048 + t4 * 512 + j * 16 + n];

        f32x4 acc[4];
#pragma unroll
        for (int t4 = 0; t4 < 4; t4++) acc[t4] = f32x4{0.f, 0.f, 0.f, 0.f};

        if (t > 0) {
            const int pp = dir ? (p + 1) : (p - 1);
            // wave w polls its quarter: s = w*4 .. w*4+3
            const uint32_t* hbase = hxp + ((size_t)pp * 16 + n) * 256 + q * 4;
            u32x4 Ah[4];
            for (;;) {
#pragma unroll
                for (int si = 0; si < 4; si++) {
                    const uint32_t* ap = hbase + (w * 4 + si) * 16;
                    asm volatile("global_load_dwordx4 %0, %1, off sc1"
                                 : "=v"(Ah[si]) : "v"(ap) : "memory");
                }
                asm volatile("s_waitcnt vmcnt(0)" ::: "memory");
                uint32_t mx = 0;
#pragma unroll
                for (int si = 0; si < 4; si++)
#pragma unroll
                    for (int wd = 0; wd < 4; wd++) mx = (Ah[si][wd] > mx) ? Ah[si][wd] : mx;
                if (__ballot(mx == SENT) == 0ull) break;
            }
            // deposit quarter into LDS chunks
#pragma unroll
            for (int si = 0; si < 4; si++) {
                int s = w * 4 + si;
                *(u32x4*)&lh[buf][s * 512 + q * 128 + n * 8] = Ah[si];
            }
            __syncthreads();
            // full A from LDS
#pragma unroll
            for (int s = 0; s < 16; s++) {
                s16x8 Af = *(const s16x8*)&lh[buf][s * 512 + q * 128 + n * 8];
#pragma unroll
                for (int t4 = 0; t4 < 4; t4++)
                    acc[t4] = __builtin_amdgcn_mfma_f32_16x16x32_bf16(Af, Bf[t4][s], acc[t4], 0, 0, 0);
            }
        }

        float g4[4][4];
#pragma unroll
        for (int t4 = 0; t4 < 4; t4++)
#pragma unroll
            for (int i = 0; i < 4; i++)
                g4[t4][i] = acc[t4][i] + bf2f(xv[t4][i]);

#pragma unroll
        for (int i = 0; i < 4; i++) {
            float ig = sigm(g4[0][i]);
            float fg = sigm(g4[1][i]);
            float gg = tanh_f(g4[2][i]);
            float og = sigm(g4[3][i]);
            c[i] = fg * c[i] + ig * gg;
            float hv = og * tanh_f(c[i]);
            uint32_t mine = (uint32_t)f2bf(hv);
            uint32_t part = __shfl_xor(mine, 1);
            if ((n & 1) == 0) {
                uint32_t pack = mine | (part << 16);  // lo = even col
                __hip_atomic_store(hxp + ((size_t)p * 16 + 4 * q + i) * 256 + j * 8 + (n >> 1),
                                   pack, __ATOMIC_RELAXED, __HIP_MEMORY_SCOPE_AGENT);
            }
        }
        // stores fly to the coherence point on their own; consumers detect
        // them by value (sentinel).
    }
}

// ---------------------------------------------------------------------------
// Span mean-pool + LayerNorm1. One block per (b,s). Reads packed hx.
// ---------------------------------------------------------------------------
__global__ __launch_bounds__(256) void kpool(const uint32_t* __restrict__ hx,
                                             const int* __restrict__ heads,
                                             const int* __restrict__ tails,
                                             const float* __restrict__ g,
                                             const float* __restrict__ bb,
                                             float* __restrict__ feat,
                                             uint16_t* __restrict__ featb) {
    const int m = blockIdx.x;
    const int b = m >> 5;
    const int tid = threadIdx.x;
    const int h0 = tid * 4;
    const int dir = h0 >> 9, hid = h0 & 511;
    int p0 = heads[m] + 1; if (p0 < 0) p0 = 0;
    int p1 = tails[m];     if (p1 > 1024) p1 = 1024;
    float a0 = 0, a1 = 0, a2 = 0, a3 = 0;
    int cnt = p1 - p0; if (cnt < 1) cnt = 1;
    for (int p = p0; p < p1; p++) {
        const uint32_t* e = hx + (((size_t)dir * 1024 + p) * 16 + b) * 256 + (hid >> 1);
        uint32_t w0 = e[0], w1 = e[1];
        a0 += bf2f((uint16_t)(w0 & 0xffff)); a1 += bf2f((uint16_t)(w0 >> 16));
        a2 += bf2f((uint16_t)(w1 & 0xffff)); a3 += bf2f((uint16_t)(w1 >> 16));
    }
    float inv = 1.0f / (float)cnt;
    float x0 = a0 * inv, x1 = a1 * inv, x2 = a2 * inv, x3 = a3 * inv;
    float ls = x0 + x1 + x2 + x3;
    float lq = x0 * x0 + x1 * x1 + x2 * x2 + x3 * x3;
#pragma unroll
    for (int o = 32; o > 0; o >>= 1) { ls += __shfl_down(ls, o); lq += __shfl_down(lq, o); }
    __shared__ float rs_[4], rq_[4], st_[2];
    const int lane = tid & 63, wid = tid >> 6;
    if (lane == 0) { rs_[wid] = ls; rq_[wid] = lq; }
    __syncthreads();
    if (tid == 0) {
        float S = rs_[0] + rs_[1] + rs_[2] + rs_[3];
        float Q = rq_[0] + rq_[1] + rq_[2] + rq_[3];
        float mean = S * (1.0f / 1024.0f);
        float var = Q * (1.0f / 1024.0f) - mean * mean;
        st_[0] = mean;
        st_[1] = rsqrtf(var + 1e-7f);
    }
    __syncthreads();
    float mean = st_[0], rstd = st_[1];
    size_t ob = (size_t)m * 1024 + h0;
    float y0 = (x0 - mean) * rstd * g[h0 + 0] + bb[h0 + 0];
    float y1 = (x1 - mean) * rstd * g[h0 + 1] + bb[h0 + 1];
    float y2 = (x2 - mean) * rstd * g[h0 + 2] + bb[h0 + 2];
    float y3 = (x3 - mean) * rstd * g[h0 + 3] + bb[h0 + 3];
    feat[ob + 0] = y0; feat[ob + 1] = y1; feat[ob + 2] = y2; feat[ob + 3] = y3;
    featb[ob + 0] = f2bf(y0); featb[ob + 1] = f2bf(y1);
    featb[ob + 2] = f2bf(y2); featb[ob + 3] = f2bf(y3);
}

// ---------------------------------------------------------------------------
// Attention over S=32, per (b, head). One wave per block.
// ---------------------------------------------------------------------------
__global__ __launch_bounds__(64) void kattn(const uint16_t* __restrict__ qkv,
                                            const int* __restrict__ am,
                                            uint16_t* __restrict__ ctxb) {
    const int bb_ = blockIdx.x >> 4, nh = blockIdx.x & 15;
    const int lane = threadIdx.x;
    __shared__ float qs[32][65], ks[32][65], vs[32][65];
    __shared__ float ps[32][33];
    for (int s = 0; s < 32; s++) {
        const uint16_t* base = qkv + (size_t)(bb_ * 32 + s) * 3072 + nh * 64;
        qs[s][lane] = bf2f(base[lane]);
        ks[s][lane] = bf2f(base[1024 + lane]);
        vs[s][lane] = bf2f(base[2048 + lane]);
    }
    __syncthreads();
    const int r = lane >> 1, ch = (lane & 1) * 16;
    const int amr = am[bb_ * 32 + r];
    float sc[16];
#pragma unroll
    for (int c0 = 0; c0 < 16; c0++) {
        int cc = ch + c0;
        float a = 0;
        for (int d = 0; d < 64; d++) a += qs[r][d] * ks[cc][d];
        a *= 0.125f;
        if (!(amr && am[bb_ * 32 + cc])) a = -1e9f;
        sc[c0] = a;
    }
    float mx = sc[0];
#pragma unroll
    for (int c0 = 1; c0 < 16; c0++) mx = fmaxf(mx, sc[c0]);
    mx = fmaxf(mx, __shfl_xor(mx, 1));
    float se = 0;
#pragma unroll
    for (int c0 = 0; c0 < 16; c0++) { sc[c0] = __expf(sc[c0] - mx); se += sc[c0]; }
    se += __shfl_xor(se, 1);
    float inv = __builtin_amdgcn_rcpf(se);
#pragma unroll
    for (int c0 = 0; c0 < 16; c0++) ps[r][ch + c0] = sc[c0] * inv;
    __syncthreads();
    for (int r2 = 0; r2 < 32; r2++) {
        float a = 0;
        for (int cc = 0; cc < 32; cc++) a += ps[r2][cc] * vs[cc][lane];
        ctxb[(size_t)(bb_ * 32 + r2) * 1024 + nh * 64 + lane] = f2bf(a);
    }
}

// ---------------------------------------------------------------------------
// LN2 over (oproj + feat residual)
// ---------------------------------------------------------------------------
__global__ __launch_bounds__(256) void kln2(const uint16_t* __restrict__ oproj,
                                            const float* __restrict__ feat,
                                            const float* __restrict__ g,
                                            const float* __restrict__ bb,
                                            float* __restrict__ feat2) {
    const int m = blockIdx.x, tid = threadIdx.x;
    const int h0 = tid * 4;
    size_t base = (size_t)m * 1024 + h0;
    u16x4 ov = *(const u16x4*)(oproj + base);
    float x0 = bf2f(ov[0]) + feat[base + 0];
    float x1 = bf2f(ov[1]) + feat[base + 1];
    float x2 = bf2f(ov[2]) + feat[base + 2];
    float x3 = bf2f(ov[3]) + feat[base + 3];
    float ls = x0 + x1 + x2 + x3;
    float lq = x0 * x0 + x1 * x1 + x2 * x2 + x3 * x3;
#pragma unroll
    for (int o = 32; o > 0; o >>= 1) { ls += __shfl_down(ls, o); lq += __shfl_down(lq, o); }
    __shared__ float rs_[4], rq_[4], st_[2];
    const int lane = tid & 63, wid = tid >> 6;
    if (lane == 0) { rs_[wid] = ls; rq_[wid] = lq; }
    __syncthreads();
    if (tid == 0) {
        float S = rs_[0] + rs_[1] + rs_[2] + rs_[3];
        float Q = rq_[0] + rq_[1] + rq_[2] + rq_[3];
        float mean = S * (1.0f / 1024.0f);
        float var = Q * (1.0f / 1024.0f) - mean * mean;
        st_[0] = mean;
        st_[1] = rsqrtf(var + 1e-7f);
    }
    __syncthreads();
    float mean = st_[0], rstd = st_[1];
    feat2[base + 0] = (x0 - mean) * rstd * g[h0 + 0] + bb[h0 + 0];
    feat2[base + 1] = (x1 - mean) * rstd * g[h0 + 1] + bb[h0 + 1];
    feat2[base + 2] = (x2 - mean) * rstd * g[h0 + 2] + bb[h0 + 2];
    feat2[base + 3] = (x3 - mean) * rstd * g[h0 + 3] + bb[h0 + 3];
}

// ---------------------------------------------------------------------------
// Classifier + CE + focal. One wave per (b,s); atomic partials.
// ---------------------------------------------------------------------------
__global__ __launch_bounds__(64) void kloss(const float* __restrict__ feat2,
                                            const float* __restrict__ Wc,
                                            const float* __restrict__ bc,
                                            const int* __restrict__ labels,
                                            const int* __restrict__ am,
                                            const float* __restrict__ wf,
                                            float* __restrict__ accum) {
    const int m = blockIdx.x, lane = threadIdx.x;
    float l0 = 0, l1 = 0, l2 = 0;
    for (int k = lane; k < 1024; k += 64) {
        float f = feat2[(size_t)m * 1024 + k];
        l0 += f * Wc[k * 3 + 0];
        l1 += f * Wc[k * 3 + 1];
        l2 += f * Wc[k * 3 + 2];
    }
#pragma unroll
    for (int o = 32; o > 0; o >>= 1) {
        l0 += __shfl_down(l0, o);
        l1 += __shfl_down(l1, o);
        l2 += __shfl_down(l2, o);
    }
    if (lane == 0) {
        l0 += bc[0]; l1 += bc[1]; l2 += bc[2];
        float mx = fmaxf(l0, fmaxf(l1, l2));
        float e0 = __expf(l0 - mx), e1 = __expf(l1 - mx), e2 = __expf(l2 - mx);
        float lse = mx + __logf(e0 + e1 + e2);
        float lp[3] = {l0 - lse, l1 - lse, l2 - lse};
        int lab = labels[m];
        float validf = (lab >= 0) ? 1.0f : 0.0f;
        int labc = lab < 0 ? 0 : lab;
        float amv = (am[m] != 0) ? 1.0f : 0.0f;
        float spanm = amv * validf;
        float ce = -lp[labc] * wf[m];
        float pt = __expf(lp[labc]);
        float om = 1.0f - pt;
        float ft = -(om * om * lp[labc]);
        atomicAdd(accum + 0, ce * spanm);
        atomicAdd(accum + 1, spanm);
        atomicAdd(accum + 2, ft * validf);
        atomicAdd(accum + 3, validf);
    }
}

__global__ void kfinal(const float* __restrict__ accum, float* __restrict__ out) {
    out[0] = accum[0] / fmaxf(accum[1], 1.0f) + accum[2] / fmaxf(accum[3], 1.0f);
}

// ---------------------------------------------------------------------------
extern "C" void kernel_launch(void* const* d_in, const int* in_sizes, int n_in,
                              void* d_out, int out_size, void* d_ws, size_t ws_size,
                              hipStream_t stream) {
    const float* hs   = (const float*)d_in[0];
    const int* heads  = (const int*)d_in[1];
    const int* tails  = (const int*)d_in[2];
    const int* amask  = (const int*)d_in[3];
    const int* labels = (const int*)d_in[4];
    const float* wfac = (const float*)d_in[5];
    const float* wihf = (const float*)d_in[6];
    const float* whhf = (const float*)d_in[7];
    const float* lbf  = (const float*)d_in[8];
    const float* wihb = (const float*)d_in[9];
    const float* whhb = (const float*)d_in[10];
    const float* lbb  = (const float*)d_in[11];
    const float* ln1g = (const float*)d_in[12];
    const float* ln1b = (const float*)d_in[13];
    const float* Wq   = (const float*)d_in[14];
    const float* bq   = (const float*)d_in[15];
    const float* Wk   = (const float*)d_in[16];
    const float* bk   = (const float*)d_in[17];
    const float* Wv   = (const float*)d_in[18];
    const float* bv   = (const float*)d_in[19];
    const float* Wo   = (const float*)d_in[20];
    const float* bo   = (const float*)d_in[21];
    const float* ln2g = (const float*)d_in[22];
    const float* ln2b = (const float*)d_in[23];
    const float* Wc   = (const float*)d_in[24];
    const float* bc   = (const float*)d_in[25];

    char* ws = (char*)d_ws;
    float* accum    = (float*)(ws + 1024);
    uint16_t* whhbf = (uint16_t*)(ws + 4096);
    uint16_t* wihbf = (uint16_t*)(ws + 4198400);
    uint16_t* wqkvo = (uint16_t*)(ws + 12587008);
    float* biasqkv  = (float*)(ws + 20975616);
    uint16_t* xs    = (uint16_t*)(ws + 20987904);
    uint32_t* hx    = (uint32_t*)(ws + 155205632);    // 33.55 MB packed h
    float* feat     = (float*)(ws + 188760064);
    uint16_t* featb = (uint16_t*)(ws + 190857216);
    uint16_t* qkvb  = (uint16_t*)(ws + 191905792);
    uint16_t* ctxb  = (uint16_t*)(ws + 195051520);
    uint16_t* oprojb= (uint16_t*)(ws + 196100096);
    float* feat2    = (float*)(ws + 197148672);       // end ~199.25 MB

    hipMemsetAsync(ws, 0, 4096, stream);  // loss accumulators

    kinit<<<8192, 256, 0, stream>>>(hx);  // sentinel-fill h exchange buffer

    kprep<<<24588, 256, 0, stream>>>(wihf, wihb, whhf, whhb, bq, bk, bv, wihbf, whhbf, biasqkv);
    ktrans<<<dim3(32, 32, 4), dim3(32, 8), 0, stream>>>(Wq, Wk, Wv, Wo, wqkvo);

    gemm_k<1><<<dim3(16, 128), 256, 0, stream>>>(hs, wihbf, lbf, xs, 16384, 2048);
    gemm_k<1><<<dim3(16, 128), 256, 0, stream>>>(hs, wihbf + (size_t)2048 * 1024, lbb,
                                                 xs + (size_t)16384 * 2048, 16384, 2048);

    krecur<<<16, 256, 0, stream>>>(whhbf, xs, hx);

    kpool<<<512, 256, 0, stream>>>(hx, heads, tails, ln1g, ln1b, feat, featb);

    gemm_k<0><<<dim3(24, 4), 256, 0, stream>>>(featb, wqkvo, biasqkv, qkvb, 512, 3072);

    kattn<<<256, 64, 0, stream>>>(qkvb, amask, ctxb);

    gemm_k<0><<<dim3(8, 4), 256, 0, stream>>>(ctxb, wqkvo + (size_t)3072 * 1024, bo, oprojb, 512, 1024);

    kln2<<<512, 256, 0, stream>>>(oprojb, feat, ln2g, ln2b, feat2);
    kloss<<<512, 64, 0, stream>>>(feat2, Wc, bc, labels, amask, wfac, accum);
    kfinal<<<1, 1, 0, stream>>>(accum, (float*)d_out);
}